// Round 19
// baseline (449.442 us; speedup 1.0000x reference)
//
#include <hip/hip_runtime.h>

#define HDIM 64
#define STEPS 3

__device__ __forceinline__ float bf2f(unsigned short u) {
  return __uint_as_float(((unsigned)u) << 16);
}
__device__ __forceinline__ unsigned short f2bf(float f) {
  unsigned u = __float_as_uint(f);
  unsigned r = (u + 0x7FFFu + ((u >> 16) & 1u)) >> 16;  // round-nearest-even
  return (unsigned short)r;
}

// ---------------- embed: x[i] = emb[tokens[i]] (fp32 + bf16 mirror) ----------------
__global__ __launch_bounds__(256) void k_embed(const int* __restrict__ tokens,
                                               const float* __restrict__ emb,
                                               float* __restrict__ x,
                                               unsigned short* __restrict__ xbf, int n) {
  int i = blockIdx.x * 256 + threadIdx.x;
  if (i < n * HDIM) {
    int node = i >> 6;
    int h = i & 63;
    float v = emb[tokens[node] * HDIM + h];
    x[i] = v;
    xbf[i] = f2bf(v);
  }
}

// ---------------- one-time prep: K-major float4 weight layouts ----------------
__global__ __launch_bounds__(256) void k_prep(const float* __restrict__ W,
                                              const float* __restrict__ w_ih,
                                              const float* __restrict__ w_hh,
                                              float* __restrict__ wc,
                                              float* __restrict__ whT) {
  int o = blockIdx.x * 256 + threadIdx.x;
  const int per = HDIM * 3 * HDIM;  // 12288
  if (o >= STEPS * per) return;
  int s = o / per;
  int rem = o - s * per;
  int q = rem & 3;
  int lane = (rem >> 2) & 63;
  int gj = rem >> 8;         // kk16*3+gate
  int gate = gj % 3;
  int kk16 = gj / 3;
  int k = kk16 * 4 + q;
  int j = gate * 64 + lane;
  if (o < per) {
    whT[o] = w_hh[j * HDIM + k];
  }
  const float4* a4 = (const float4*)(W + (size_t)s * HDIM * HDIM + (size_t)k * HDIM);
  const float4* b4 = (const float4*)(w_ih + (size_t)j * HDIM);
  float acc = 0.f;
#pragma unroll
  for (int t = 0; t < HDIM / 4; ++t) {
    float4 a = a4[t];
    float4 b = b4[t];
    acc = fmaf(a.x, b.x, acc);
    acc = fmaf(a.y, b.y, acc);
    acc = fmaf(a.z, b.z, acc);
    acc = fmaf(a.w, b.w, acc);
  }
  wc[o] = acc;
}

// ---------------- CSR build ----------------
__global__ __launch_bounds__(256) void k_hist(const int* __restrict__ dsts,
                                              int* __restrict__ deg, int ne) {
  int e = blockIdx.x * 256 + threadIdx.x;
  if (e < ne) atomicAdd(&deg[dsts[e]], 1);
}

__global__ __launch_bounds__(256) void k_scan1(const int* __restrict__ deg,
                                               int* __restrict__ bsum, int n) {
  __shared__ int s[256];
  const int tid = threadIdx.x;
  int i = blockIdx.x * 256 + tid;
  s[tid] = (i < n) ? deg[i] : 0;
  __syncthreads();
  for (int off = 128; off > 0; off >>= 1) {
    if (tid < off) s[tid] += s[tid + off];
    __syncthreads();
  }
  if (tid == 0) bsum[blockIdx.x] = s[0];
}

__global__ __launch_bounds__(1024) void k_scan2(int* __restrict__ bsum, int nb) {
  __shared__ int s[1024];
  const int tid = threadIdx.x;
  int carry = 0;
  for (int base = 0; base < nb; base += 1024) {
    int i = base + tid;
    int v = (i < nb) ? bsum[i] : 0;
    s[tid] = v;
    __syncthreads();
    for (int off = 1; off < 1024; off <<= 1) {
      int t = (tid >= off) ? s[tid - off] : 0;
      __syncthreads();
      s[tid] += t;
      __syncthreads();
    }
    if (i < nb) bsum[i] = carry + s[tid] - v;  // exclusive
    carry += s[1023];
    __syncthreads();
  }
}

__global__ __launch_bounds__(256) void k_scan3(const int* __restrict__ deg,
                                               const int* __restrict__ bsum,
                                               int* __restrict__ rowptr,
                                               int* __restrict__ cursor, int n) {
  __shared__ int s[256];
  const int tid = threadIdx.x;
  int i = blockIdx.x * 256 + tid;
  int v = (i < n) ? deg[i] : 0;
  s[tid] = v;
  __syncthreads();
  for (int off = 1; off < 256; off <<= 1) {
    int t = (tid >= off) ? s[tid - off] : 0;
    __syncthreads();
    s[tid] += t;
    __syncthreads();
  }
  int excl = bsum[blockIdx.x] + s[tid] - v;
  if (i < n) {
    rowptr[i] = excl;
    cursor[i] = excl;
    if (i == n - 1) rowptr[n] = excl + v;
  }
}

__global__ __launch_bounds__(256) void k_fill(const int* __restrict__ srcs,
                                              const int* __restrict__ dsts,
                                              int* __restrict__ cursor,
                                              int* __restrict__ eidx, int ne) {
  int e = blockIdx.x * 256 + threadIdx.x;
  if (e < ne) {
    int d = dsts[e];
    int p = atomicAdd(&cursor[d], 1);
    eidx[p] = srcs[e];
  }
}

// ---------------- FUSED gather + GRU: xout = GRU(sum_nbrs(xin) @ Wc, xin) ----------------
// R18 structure (wc LDS 48KB K-major float4, whT global float4, 512thr, (512,2)).
// NEW: neighbor rows gathered from a bf16 MIRROR of x (6.4MB ~ per-XCD L2) ->
// per-edge miss bytes halve and L2 hit-rate jumps. All arithmetic stays fp32;
// own-row h reads the fp32 buffer; epilogue writes fp32 + bf16(RNE) mirrors.
__global__ __launch_bounds__(512, 2) void k_fgru(const int* __restrict__ rowptr,
                                                 const int* __restrict__ eidx,
                                                 const ushort4* __restrict__ xbf4,
                                                 const float* __restrict__ xin,
                                                 float* __restrict__ xout,
                                                 unsigned short* __restrict__ xbf_out,
                                                 const float* __restrict__ wc_g,
                                                 const float4* __restrict__ wh4,
                                                 const float* __restrict__ b_ih,
                                                 const float* __restrict__ b_hh,
                                                 int n) {
  __shared__ float wiT[HDIM * 3 * HDIM];   // 48KB, K-major float4 layout
  __shared__ float abuf[8][4][HDIM];       // 8KB
  __shared__ float hbuf[8][4][HDIM];       // 8KB
  for (int t = threadIdx.x; t < HDIM * 3 * HDIM; t += 512) wiT[t] = wc_g[t];
  __syncthreads();

  const int lane = threadIdx.x & 63;
  const int wid = threadIdx.x >> 6;  // 0..7
  const int NG = (n + 3) >> 2;
  int g = blockIdx.x * 8 + wid;
  if (g >= NG) return;

  const int node0 = g * 4;
  const int grp = lane >> 4;    // edge stream 0..3
  const int cl = lane & 15;     // 4-channel chunk

  // --- gather phase: 4 nodes of this wave (R11 form, bf16 rows) ---
#pragma unroll
  for (int i = 0; i < 4; ++i) {
    int node = node0 + i;
    float4 acc = make_float4(0.f, 0.f, 0.f, 0.f);
    if (node < n) {
      const int lo = rowptr[node], hi = rowptr[node + 1];
      int e = lo + grp;
      for (; e + 4 < hi; e += 8) {
        int s0 = eidx[e];
        int s1 = eidx[e + 4];
        ushort4 u0 = xbf4[(size_t)s0 * 16 + cl];
        ushort4 u1 = xbf4[(size_t)s1 * 16 + cl];
        acc.x += bf2f(u0.x) + bf2f(u1.x);
        acc.y += bf2f(u0.y) + bf2f(u1.y);
        acc.z += bf2f(u0.z) + bf2f(u1.z);
        acc.w += bf2f(u0.w) + bf2f(u1.w);
      }
      if (e < hi) {
        int s0 = eidx[e];
        ushort4 u0 = xbf4[(size_t)s0 * 16 + cl];
        acc.x += bf2f(u0.x); acc.y += bf2f(u0.y);
        acc.z += bf2f(u0.z); acc.w += bf2f(u0.w);
      }
    }
#pragma unroll
    for (int off = 16; off < 64; off <<= 1) {
      acc.x += __shfl_xor(acc.x, off);
      acc.y += __shfl_xor(acc.y, off);
      acc.z += __shfl_xor(acc.z, off);
      acc.w += __shfl_xor(acc.w, off);
    }
    if (grp == 0) *((float4*)&abuf[wid][i][cl * 4]) = acc;
  }

  // --- own rows (fp32, exact) ---
  float xv[4];
#pragma unroll
  for (int i = 0; i < 4; ++i) {
    int node = node0 + i;
    xv[i] = (node < n) ? xin[(size_t)node * HDIM + lane] : 0.f;
    hbuf[wid][i][lane] = xv[i];
  }

  const float Br = b_ih[lane] + b_hh[lane];
  const float Bz = b_ih[HDIM + lane] + b_hh[HDIM + lane];
  const float Bin = b_ih[2 * HDIM + lane];
  const float Bhn = b_hh[2 * HDIM + lane];

  float ar[4] = {0, 0, 0, 0}, az[4] = {0, 0, 0, 0}, an[4] = {0, 0, 0, 0};
  float hr[4] = {0, 0, 0, 0}, hz[4] = {0, 0, 0, 0}, hn[4] = {0, 0, 0, 0};

#pragma unroll 1
  for (int kk16 = 0; kk16 < 16; ++kk16) {
    const float4 wr4 = *(const float4*)&wiT[(((kk16 * 3 + 0) * 64) + lane) * 4];
    const float4 wz4 = *(const float4*)&wiT[(((kk16 * 3 + 1) * 64) + lane) * 4];
    const float4 wn4 = *(const float4*)&wiT[(((kk16 * 3 + 2) * 64) + lane) * 4];
    const float4 vr4 = wh4[(kk16 * 3 + 0) * 64 + lane];
    const float4 vz4 = wh4[(kk16 * 3 + 1) * 64 + lane];
    const float4 vn4 = wh4[(kk16 * 3 + 2) * 64 + lane];
#pragma unroll
    for (int i = 0; i < 4; ++i) {
      const float4 a4 = *(const float4*)&abuf[wid][i][kk16 * 4];  // uniform, broadcast
      const float4 h4 = *(const float4*)&hbuf[wid][i][kk16 * 4];
      ar[i] = fmaf(a4.x, wr4.x, ar[i]); az[i] = fmaf(a4.x, wz4.x, az[i]); an[i] = fmaf(a4.x, wn4.x, an[i]);
      hr[i] = fmaf(h4.x, vr4.x, hr[i]); hz[i] = fmaf(h4.x, vz4.x, hz[i]); hn[i] = fmaf(h4.x, vn4.x, hn[i]);
      ar[i] = fmaf(a4.y, wr4.y, ar[i]); az[i] = fmaf(a4.y, wz4.y, az[i]); an[i] = fmaf(a4.y, wn4.y, an[i]);
      hr[i] = fmaf(h4.y, vr4.y, hr[i]); hz[i] = fmaf(h4.y, vz4.y, hz[i]); hn[i] = fmaf(h4.y, vn4.y, hn[i]);
      ar[i] = fmaf(a4.z, wr4.z, ar[i]); az[i] = fmaf(a4.z, wz4.z, az[i]); an[i] = fmaf(a4.z, wn4.z, an[i]);
      hr[i] = fmaf(h4.z, vr4.z, hr[i]); hz[i] = fmaf(h4.z, vz4.z, hz[i]); hn[i] = fmaf(h4.z, vn4.z, hn[i]);
      ar[i] = fmaf(a4.w, wr4.w, ar[i]); az[i] = fmaf(a4.w, wz4.w, az[i]); an[i] = fmaf(a4.w, wn4.w, an[i]);
      hr[i] = fmaf(h4.w, vr4.w, hr[i]); hz[i] = fmaf(h4.w, vz4.w, hz[i]); hn[i] = fmaf(h4.w, vn4.w, hn[i]);
    }
  }

#pragma unroll
  for (int i = 0; i < 4; ++i) {
    int node = node0 + i;
    if (node < n) {
      float r = 1.f / (1.f + __expf(-(ar[i] + hr[i] + Br)));
      float z = 1.f / (1.f + __expf(-(az[i] + hz[i] + Bz)));
      float nn = tanhf((an[i] + Bin) + r * (hn[i] + Bhn));
      float val = (1.f - z) * nn + z * xv[i];
      xout[(size_t)node * HDIM + lane] = val;
      xbf_out[(size_t)node * HDIM + lane] = f2bf(val);
    }
  }
}

// ---------------- per-graph mean pool of relu(x); batch sorted ----------------
__device__ __forceinline__ int lower_bound_i(const int* __restrict__ a, int n, int v) {
  int lo = 0, hi = n;
  while (lo < hi) {
    int mid = (lo + hi) >> 1;
    if (a[mid] < v) lo = mid + 1; else hi = mid;
  }
  return lo;
}

__global__ __launch_bounds__(256) void k_pool(const float* __restrict__ x,
                                              const int* __restrict__ batch,
                                              float* __restrict__ pooled,
                                              int n) {
  int g = blockIdx.x;
  int lo = lower_bound_i(batch, n, g);
  int hi = lower_bound_i(batch, n, g + 1);
  const int lane = threadIdx.x & 63;
  const int w = threadIdx.x >> 6;  // 0..3
  float acc = 0.f;
  for (int i = lo + w; i < hi; i += 4) {
    acc += fmaxf(x[i * HDIM + lane], 0.f);
  }
  __shared__ float red[4][HDIM];
  red[w][lane] = acc;
  __syncthreads();
  if (w == 0) {
    float s = red[0][lane] + red[1][lane] + red[2][lane] + red[3][lane];
    float cnt = (float)(hi - lo);
    pooled[g * HDIM + lane] = s / fmaxf(cnt, 1.f);
  }
}

// ---------------- head ----------------
__global__ __launch_bounds__(256) void k_head(const float* __restrict__ pooled,
                                              const float* __restrict__ lin1_w,
                                              const float* __restrict__ lin1_b,
                                              const float* __restrict__ lout_w,
                                              const float* __restrict__ lout_b,
                                              float* __restrict__ out, int G) {
  __shared__ float P[128 * HDIM];
  __shared__ float W1T[HDIM * HDIM];
  __shared__ float H1[128 * HDIM];
  for (int t = threadIdx.x; t < G * HDIM; t += 256) P[t] = pooled[t];
  for (int t = threadIdx.x; t < HDIM * HDIM; t += 256) {
    int j = t & 63, k = t >> 6;
    W1T[k * HDIM + j] = lin1_w[j * HDIM + k];
  }
  __syncthreads();
  for (int idx = threadIdx.x; idx < G * HDIM; idx += 256) {
    int g = idx >> 6, j = idx & 63;
    float acc = lin1_b[j];
#pragma unroll
    for (int k = 0; k < HDIM; ++k) acc = fmaf(P[g * HDIM + k], W1T[k * HDIM + j], acc);
    H1[idx] = fmaxf(acc, 0.f);
  }
  __syncthreads();
  for (int idx = threadIdx.x; idx < G * 2; idx += 256) {
    int g = idx >> 1, c = idx & 1;
    float acc = lout_b[c];
#pragma unroll
    for (int j = 0; j < HDIM; ++j) acc = fmaf(H1[g * HDIM + j], lout_w[c * HDIM + j], acc);
    out[idx] = acc;
  }
}

extern "C" void kernel_launch(void* const* d_in, const int* in_sizes, int n_in,
                              void* d_out, int out_size, void* d_ws, size_t ws_size,
                              hipStream_t stream) {
  const int* tokens   = (const int*)d_in[0];
  const int* edge_idx = (const int*)d_in[1];
  const int* batch    = (const int*)d_in[2];
  const float* emb    = (const float*)d_in[3];
  const float* ggnn_w = (const float*)d_in[4];
  const float* w_ih   = (const float*)d_in[5];
  const float* w_hh   = (const float*)d_in[6];
  const float* b_ih   = (const float*)d_in[7];
  const float* b_hh   = (const float*)d_in[8];
  const float* lin1_w = (const float*)d_in[9];
  const float* lin1_b = (const float*)d_in[10];
  const float* lout_w = (const float*)d_in[11];
  const float* lout_b = (const float*)d_in[12];

  const int N = in_sizes[0];
  const int E = in_sizes[1] / 2;
  const int G = out_size / 2;

  const int* srcs = edge_idx;
  const int* dsts = edge_idx + E;

  char* ws = (char*)d_ws;
  size_t off = 0;
  auto take = [&](size_t nbytes) -> char* {
    char* p = ws + off;
    off += (nbytes + 255) & ~(size_t)255;
    return p;
  };
  size_t rowBytes = (size_t)N * HDIM * sizeof(float);
  size_t bfBytes  = (size_t)N * HDIM * sizeof(unsigned short);
  const int nb256 = (N + 255) / 256;
  float* xA     = (float*)take(rowBytes);
  float* xB     = (float*)take(rowBytes);
  unsigned short* bfA = (unsigned short*)take(bfBytes);
  unsigned short* bfB = (unsigned short*)take(bfBytes);
  float* pooled = (float*)take((size_t)G * HDIM * sizeof(float));
  float* whT_g  = (float*)take(HDIM * 3 * HDIM * sizeof(float));
  float* wc_g   = (float*)take((size_t)STEPS * HDIM * 3 * HDIM * sizeof(float));
  int* rowptr   = (int*)take((size_t)(N + 1) * sizeof(int));
  int* cursor   = (int*)take((size_t)N * sizeof(int));  // also used as deg
  int* bsum     = (int*)take((size_t)nb256 * sizeof(int));
  int* eidx     = (int*)take((size_t)E * sizeof(int));

  // --- one-time precompute: K-major float4 weights + CSR by dst ---
  {
    const int total = STEPS * HDIM * 3 * HDIM;
    k_prep<<<(total + 255) / 256, 256, 0, stream>>>(ggnn_w, w_ih, w_hh, wc_g, whT_g);
  }
  hipMemsetAsync(cursor, 0, (size_t)N * sizeof(int), stream);
  k_hist<<<(E + 255) / 256, 256, 0, stream>>>(dsts, cursor, E);
  k_scan1<<<nb256, 256, 0, stream>>>(cursor, bsum, N);
  k_scan2<<<1, 1024, 0, stream>>>(bsum, nb256);
  k_scan3<<<nb256, 256, 0, stream>>>(cursor, bsum, rowptr, cursor, N);
  k_fill<<<(E + 255) / 256, 256, 0, stream>>>(srcs, dsts, cursor, eidx, E);

  // --- embed (fp32 + bf16 mirror) ---
  k_embed<<<(N * HDIM + 255) / 256, 256, 0, stream>>>(tokens, emb, xA, bfA, N);

  // --- GGNN steps: fused gather+GRU, ping-pong x / xbf ---
  const int NG = (N + 3) / 4;
  const int fblocks = (NG + 7) / 8;
  float* xin = xA;
  float* xout = xB;
  unsigned short* bin = bfA;
  unsigned short* bout = bfB;
  for (int s = 0; s < STEPS; ++s) {
    k_fgru<<<fblocks, 512, 0, stream>>>(rowptr, eidx, (const ushort4*)bin, xin, xout,
                                        bout,
                                        wc_g + (size_t)s * HDIM * 3 * HDIM,
                                        (const float4*)whT_g, b_ih, b_hh, N);
    float* t1 = xin; xin = xout; xout = t1;
    unsigned short* t2 = bin; bin = bout; bout = t2;
  }

  k_pool<<<G, 256, 0, stream>>>(xin, batch, pooled, N);
  k_head<<<1, 256, 0, stream>>>(pooled, lin1_w, lin1_b, lout_w, lout_b,
                                (float*)d_out, G);
}

// Round 20
// 307.439 us; speedup vs baseline: 1.4619x; 1.4619x over previous
//
#include <hip/hip_runtime.h>

#define HDIM 64
#define STEPS 3

typedef __attribute__((ext_vector_type(8))) short s16x8;
typedef __attribute__((ext_vector_type(4))) float f32x4;

__device__ __forceinline__ float bf2f(unsigned short u) {
  return __uint_as_float(((unsigned)u) << 16);
}
__device__ __forceinline__ unsigned short f2bf(float f) {
  unsigned u = __float_as_uint(f);
  unsigned r = (u + 0x7FFFu + ((u >> 16) & 1u)) >> 16;  // RNE
  return (unsigned short)r;
}

// ---------------- embed: x[i] = emb[tokens[i]] ----------------
__global__ __launch_bounds__(256) void k_embed(const int* __restrict__ tokens,
                                               const float* __restrict__ emb,
                                               float* __restrict__ x, int n) {
  int i = blockIdx.x * 256 + threadIdx.x;
  if (i < n * HDIM) {
    int node = i >> 6;
    int h = i & 63;
    x[i] = emb[tokens[node] * HDIM + h];
  }
}

// ---------------- one-time prep: packed MFMA B-fragments (bf16 hi/lo) --------
// Logical Bmat[s][K=128][C=256]:
//   k<64  (agg): cols 0-63 wc_r, 64-127 wc_z, 128-191 wc_n, 192-255 zero
//   k>=64 (h):   cols 0-63 wh_r, 64-127 wh_z, 128-191 zero, 192-255 wh_n
// wc[k][j] = dot(W_s[k][:], w_ih[j][:]);  wh[k'][j] = w_hh[j][k']
// Fragment layout for mfma_f32_16x16x32_bf16 B-operand:
//   frag fid = c2*4 + t (c2: 16-col tile, t: 32-k tile); within frag,
//   element lane*8+j = Bmat[t*32+(lane>>4)*8+j][c2*16+(lane&15)]
__global__ __launch_bounds__(256) void k_prep(const float* __restrict__ W,
                                              const float* __restrict__ w_ih,
                                              const float* __restrict__ w_hh,
                                              unsigned short* __restrict__ wBhi,
                                              unsigned short* __restrict__ wBlo) {
  int o = blockIdx.x * 256 + threadIdx.x;
  if (o >= STEPS * 64 * 512) return;
  int s = o / 32768;
  int r1 = o & 32767;
  int fid = r1 >> 9;
  int le = r1 & 511;
  int lane = le >> 3, j = le & 7;
  int c2 = fid >> 2, t = fid & 3;
  int sec = c2 >> 2, csub = c2 & 3;        // sec: 0=r 1=z 2=gi_n 3=gh_n
  int ch = csub * 16 + (lane & 15);        // channel 0..63
  int k = t * 32 + (lane >> 4) * 8 + j;    // 0..127
  float val = 0.f;
  if (k < 64) {
    if (sec < 3) {
      int jcol = sec * 64 + ch;            // w_ih row
      const float4* a4 = (const float4*)(W + (size_t)s * HDIM * HDIM + (size_t)k * HDIM);
      const float4* b4 = (const float4*)(w_ih + (size_t)jcol * HDIM);
      float acc = 0.f;
#pragma unroll
      for (int q = 0; q < HDIM / 4; ++q) {
        float4 a = a4[q];
        float4 b = b4[q];
        acc = fmaf(a.x, b.x, acc);
        acc = fmaf(a.y, b.y, acc);
        acc = fmaf(a.z, b.z, acc);
        acc = fmaf(a.w, b.w, acc);
      }
      val = acc;
    }
  } else {
    int k2 = k - 64;
    if (sec == 0)      val = w_hh[(size_t)(0 + ch) * HDIM + k2];
    else if (sec == 1) val = w_hh[(size_t)(64 + ch) * HDIM + k2];
    else if (sec == 3) val = w_hh[(size_t)(128 + ch) * HDIM + k2];
  }
  unsigned short hi = f2bf(val);
  unsigned short lo = f2bf(val - bf2f(hi));
  wBhi[o] = hi;
  wBlo[o] = lo;
}

// ---------------- CSR build ----------------
__global__ __launch_bounds__(256) void k_hist(const int* __restrict__ dsts,
                                              int* __restrict__ deg, int ne) {
  int e = blockIdx.x * 256 + threadIdx.x;
  if (e < ne) atomicAdd(&deg[dsts[e]], 1);
}

__global__ __launch_bounds__(256) void k_scan1(const int* __restrict__ deg,
                                               int* __restrict__ bsum, int n) {
  __shared__ int s[256];
  const int tid = threadIdx.x;
  int i = blockIdx.x * 256 + tid;
  s[tid] = (i < n) ? deg[i] : 0;
  __syncthreads();
  for (int off = 128; off > 0; off >>= 1) {
    if (tid < off) s[tid] += s[tid + off];
    __syncthreads();
  }
  if (tid == 0) bsum[blockIdx.x] = s[0];
}

__global__ __launch_bounds__(1024) void k_scan2(int* __restrict__ bsum, int nb) {
  __shared__ int s[1024];
  const int tid = threadIdx.x;
  int carry = 0;
  for (int base = 0; base < nb; base += 1024) {
    int i = base + tid;
    int v = (i < nb) ? bsum[i] : 0;
    s[tid] = v;
    __syncthreads();
    for (int off = 1; off < 1024; off <<= 1) {
      int t = (tid >= off) ? s[tid - off] : 0;
      __syncthreads();
      s[tid] += t;
      __syncthreads();
    }
    if (i < nb) bsum[i] = carry + s[tid] - v;  // exclusive
    carry += s[1023];
    __syncthreads();
  }
}

__global__ __launch_bounds__(256) void k_scan3(const int* __restrict__ deg,
                                               const int* __restrict__ bsum,
                                               int* __restrict__ rowptr,
                                               int* __restrict__ cursor, int n) {
  __shared__ int s[256];
  const int tid = threadIdx.x;
  int i = blockIdx.x * 256 + tid;
  int v = (i < n) ? deg[i] : 0;
  s[tid] = v;
  __syncthreads();
  for (int off = 1; off < 256; off <<= 1) {
    int t = (tid >= off) ? s[tid - off] : 0;
    __syncthreads();
    s[tid] += t;
    __syncthreads();
  }
  int excl = bsum[blockIdx.x] + s[tid] - v;
  if (i < n) {
    rowptr[i] = excl;
    cursor[i] = excl;
    if (i == n - 1) rowptr[n] = excl + v;
  }
}

__global__ __launch_bounds__(256) void k_fill(const int* __restrict__ srcs,
                                              const int* __restrict__ dsts,
                                              int* __restrict__ cursor,
                                              int* __restrict__ eidx, int ne) {
  int e = blockIdx.x * 256 + threadIdx.x;
  if (e < ne) {
    int d = dsts[e];
    int p = atomicAdd(&cursor[d], 1);
    eidx[p] = srcs[e];
  }
}

// ---------------- FUSED gather + MFMA GRU ----------------
// 512 thr = 8 waves = two 16-node tiles (4 waves each). Each wave gathers 4
// nodes (exact R18 float4 loop, fp32) into a shared bf16 hi/lo A-tile
// [16 nodes][136] (cols 0-63 agg, 64-127 h; stride 136 -> 2-way-free banks).
// After syncthreads each wave computes its 16-channel column slab with
// mfma_f32_16x16x32_bf16 in split precision: Ah*Bh + Ah*Bl + Al*Bh.
// C/D layout (verified, guide m89): col = lane&15, row = (lane>>4)*4 + reg.
__global__ __launch_bounds__(512, 2) void k_fgru(const int* __restrict__ rowptr,
                                                 const int* __restrict__ eidx,
                                                 const float4* __restrict__ xin4,
                                                 const float* __restrict__ xin,
                                                 float* __restrict__ xout,
                                                 const unsigned short* __restrict__ wBhi_s,
                                                 const unsigned short* __restrict__ wBlo_s,
                                                 const float* __restrict__ b_ih,
                                                 const float* __restrict__ b_hh,
                                                 int n) {
  __shared__ unsigned short Ahi[2][16][136];
  __shared__ unsigned short Alo[2][16][136];

  const int lane = threadIdx.x & 63;
  const int wid = threadIdx.x >> 6;   // 0..7
  const int tile = wid >> 2;          // 0..1
  const int csub = wid & 3;           // 0..3 (channel sub-tile in phase 2)
  const int node_base = blockIdx.x * 32 + tile * 16;

  const int grp = lane >> 4;          // edge stream 0..3
  const int cl = lane & 15;           // float4 channel chunk

  // --- phase 1: gather 4 nodes (rows csub*4..+3 of this tile) + own rows ---
#pragma unroll
  for (int q = 0; q < 4; ++q) {
    int i = csub * 4 + q;
    int node = node_base + i;
    float4 acc = make_float4(0.f, 0.f, 0.f, 0.f);
    if (node < n) {
      const int lo = rowptr[node], hi = rowptr[node + 1];
      int e = lo + grp;
      for (; e + 4 < hi; e += 8) {
        int s0 = eidx[e];
        int s1 = eidx[e + 4];
        float4 v0 = xin4[(size_t)s0 * 16 + cl];
        float4 v1 = xin4[(size_t)s1 * 16 + cl];
        acc.x += v0.x + v1.x;
        acc.y += v0.y + v1.y;
        acc.z += v0.z + v1.z;
        acc.w += v0.w + v1.w;
      }
      if (e < hi) {
        int s0 = eidx[e];
        float4 v0 = xin4[(size_t)s0 * 16 + cl];
        acc.x += v0.x; acc.y += v0.y; acc.z += v0.z; acc.w += v0.w;
      }
    }
#pragma unroll
    for (int off = 16; off < 64; off <<= 1) {
      acc.x += __shfl_xor(acc.x, off);
      acc.y += __shfl_xor(acc.y, off);
      acc.z += __shfl_xor(acc.z, off);
      acc.w += __shfl_xor(acc.w, off);
    }
    if (grp == 0) {
      ushort4 hi4, lo4;
      hi4.x = f2bf(acc.x); lo4.x = f2bf(acc.x - bf2f(hi4.x));
      hi4.y = f2bf(acc.y); lo4.y = f2bf(acc.y - bf2f(hi4.y));
      hi4.z = f2bf(acc.z); lo4.z = f2bf(acc.z - bf2f(hi4.z));
      hi4.w = f2bf(acc.w); lo4.w = f2bf(acc.w - bf2f(hi4.w));
      *(ushort4*)&Ahi[tile][i][cl * 4] = hi4;
      *(ushort4*)&Alo[tile][i][cl * 4] = lo4;
    }
    float v = (node < n) ? xin[(size_t)node * HDIM + lane] : 0.f;
    unsigned short hv = f2bf(v);
    Ahi[tile][i][64 + lane] = hv;
    Alo[tile][i][64 + lane] = f2bf(v - bf2f(hv));
  }
  __syncthreads();

  // --- phase 2: MFMA over this wave's 16-channel slab ---
  const int row = lane & 15;
  const int kseg = (lane >> 4) * 8;
  s16x8 ah0 = *(const s16x8*)&Ahi[tile][row][0 + kseg];
  s16x8 ah1 = *(const s16x8*)&Ahi[tile][row][32 + kseg];
  s16x8 ah2 = *(const s16x8*)&Ahi[tile][row][64 + kseg];
  s16x8 ah3 = *(const s16x8*)&Ahi[tile][row][96 + kseg];
  s16x8 al0 = *(const s16x8*)&Alo[tile][row][0 + kseg];
  s16x8 al1 = *(const s16x8*)&Alo[tile][row][32 + kseg];
  s16x8 al2 = *(const s16x8*)&Alo[tile][row][64 + kseg];
  s16x8 al3 = *(const s16x8*)&Alo[tile][row][96 + kseg];

  const s16x8* Bh = (const s16x8*)wBhi_s;  // 64 s16x8 per fragment
  const s16x8* Bl = (const s16x8*)wBlo_s;

  f32x4 accR = {0.f, 0.f, 0.f, 0.f};
  f32x4 accZ = {0.f, 0.f, 0.f, 0.f};
  f32x4 accN = {0.f, 0.f, 0.f, 0.f};
  f32x4 accG = {0.f, 0.f, 0.f, 0.f};

#define MMA3(ACC, AH, AL, FID)                                             \
  {                                                                        \
    s16x8 bh = Bh[(FID) * 64 + lane];                                      \
    s16x8 bl = Bl[(FID) * 64 + lane];                                      \
    ACC = __builtin_amdgcn_mfma_f32_16x16x32_bf16(AH, bh, ACC, 0, 0, 0);   \
    ACC = __builtin_amdgcn_mfma_f32_16x16x32_bf16(AH, bl, ACC, 0, 0, 0);   \
    ACC = __builtin_amdgcn_mfma_f32_16x16x32_bf16(AL, bh, ACC, 0, 0, 0);   \
  }

  {  // r-gate: c2 = 0..3 band, all 4 k-tiles
    const int c2 = 0 + csub;
    MMA3(accR, ah0, al0, c2 * 4 + 0)
    MMA3(accR, ah1, al1, c2 * 4 + 1)
    MMA3(accR, ah2, al2, c2 * 4 + 2)
    MMA3(accR, ah3, al3, c2 * 4 + 3)
  }
  {  // z-gate
    const int c2 = 4 + csub;
    MMA3(accZ, ah0, al0, c2 * 4 + 0)
    MMA3(accZ, ah1, al1, c2 * 4 + 1)
    MMA3(accZ, ah2, al2, c2 * 4 + 2)
    MMA3(accZ, ah3, al3, c2 * 4 + 3)
  }
  {  // gi_n: only agg rows (k<64 -> t=0,1)
    const int c2 = 8 + csub;
    MMA3(accN, ah0, al0, c2 * 4 + 0)
    MMA3(accN, ah1, al1, c2 * 4 + 1)
  }
  {  // gh_n: only h rows (k>=64 -> t=2,3)
    const int c2 = 12 + csub;
    MMA3(accG, ah2, al2, c2 * 4 + 2)
    MMA3(accG, ah3, al3, c2 * 4 + 3)
  }
#undef MMA3

  const int ch = csub * 16 + (lane & 15);
  const float Br = b_ih[ch] + b_hh[ch];
  const float Bz = b_ih[64 + ch] + b_hh[64 + ch];
  const float Bin = b_ih[128 + ch];
  const float Bhn = b_hh[128 + ch];

#pragma unroll
  for (int reg = 0; reg < 4; ++reg) {
    int i = (lane >> 4) * 4 + reg;
    int node = node_base + i;
    if (node < n) {
      float r = 1.f / (1.f + __expf(-(accR[reg] + Br)));
      float z = 1.f / (1.f + __expf(-(accZ[reg] + Bz)));
      float nn = tanhf((accN[reg] + Bin) + r * (accG[reg] + Bhn));
      float hold = xin[(size_t)node * HDIM + ch];
      xout[(size_t)node * HDIM + ch] = (1.f - z) * nn + z * hold;
    }
  }
}

// ---------------- per-graph mean pool of relu(x); batch sorted ----------------
__device__ __forceinline__ int lower_bound_i(const int* __restrict__ a, int n, int v) {
  int lo = 0, hi = n;
  while (lo < hi) {
    int mid = (lo + hi) >> 1;
    if (a[mid] < v) lo = mid + 1; else hi = mid;
  }
  return lo;
}

__global__ __launch_bounds__(256) void k_pool(const float* __restrict__ x,
                                              const int* __restrict__ batch,
                                              float* __restrict__ pooled,
                                              int n) {
  int g = blockIdx.x;
  int lo = lower_bound_i(batch, n, g);
  int hi = lower_bound_i(batch, n, g + 1);
  const int lane = threadIdx.x & 63;
  const int w = threadIdx.x >> 6;  // 0..3
  float acc = 0.f;
  for (int i = lo + w; i < hi; i += 4) {
    acc += fmaxf(x[i * HDIM + lane], 0.f);
  }
  __shared__ float red[4][HDIM];
  red[w][lane] = acc;
  __syncthreads();
  if (w == 0) {
    float s = red[0][lane] + red[1][lane] + red[2][lane] + red[3][lane];
    float cnt = (float)(hi - lo);
    pooled[g * HDIM + lane] = s / fmaxf(cnt, 1.f);
  }
}

// ---------------- head ----------------
__global__ __launch_bounds__(256) void k_head(const float* __restrict__ pooled,
                                              const float* __restrict__ lin1_w,
                                              const float* __restrict__ lin1_b,
                                              const float* __restrict__ lout_w,
                                              const float* __restrict__ lout_b,
                                              float* __restrict__ out, int G) {
  __shared__ float P[128 * HDIM];
  __shared__ float W1T[HDIM * HDIM];
  __shared__ float H1[128 * HDIM];
  for (int t = threadIdx.x; t < G * HDIM; t += 256) P[t] = pooled[t];
  for (int t = threadIdx.x; t < HDIM * HDIM; t += 256) {
    int j = t & 63, k = t >> 6;
    W1T[k * HDIM + j] = lin1_w[j * HDIM + k];
  }
  __syncthreads();
  for (int idx = threadIdx.x; idx < G * HDIM; idx += 256) {
    int g = idx >> 6, j = idx & 63;
    float acc = lin1_b[j];
#pragma unroll
    for (int k = 0; k < HDIM; ++k) acc = fmaf(P[g * HDIM + k], W1T[k * HDIM + j], acc);
    H1[idx] = fmaxf(acc, 0.f);
  }
  __syncthreads();
  for (int idx = threadIdx.x; idx < G * 2; idx += 256) {
    int g = idx >> 1, c = idx & 1;
    float acc = lout_b[c];
#pragma unroll
    for (int j = 0; j < HDIM; ++j) acc = fmaf(H1[g * HDIM + j], lout_w[c * HDIM + j], acc);
    out[idx] = acc;
  }
}

extern "C" void kernel_launch(void* const* d_in, const int* in_sizes, int n_in,
                              void* d_out, int out_size, void* d_ws, size_t ws_size,
                              hipStream_t stream) {
  const int* tokens   = (const int*)d_in[0];
  const int* edge_idx = (const int*)d_in[1];
  const int* batch    = (const int*)d_in[2];
  const float* emb    = (const float*)d_in[3];
  const float* ggnn_w = (const float*)d_in[4];
  const float* w_ih   = (const float*)d_in[5];
  const float* w_hh   = (const float*)d_in[6];
  const float* b_ih   = (const float*)d_in[7];
  const float* b_hh   = (const float*)d_in[8];
  const float* lin1_w = (const float*)d_in[9];
  const float* lin1_b = (const float*)d_in[10];
  const float* lout_w = (const float*)d_in[11];
  const float* lout_b = (const float*)d_in[12];

  const int N = in_sizes[0];
  const int E = in_sizes[1] / 2;
  const int G = out_size / 2;

  const int* srcs = edge_idx;
  const int* dsts = edge_idx + E;

  char* ws = (char*)d_ws;
  size_t off = 0;
  auto take = [&](size_t nbytes) -> char* {
    char* p = ws + off;
    off += (nbytes + 255) & ~(size_t)255;
    return p;
  };
  size_t rowBytes = (size_t)N * HDIM * sizeof(float);
  const int nb256 = (N + 255) / 256;
  float* xA     = (float*)take(rowBytes);
  float* xB     = (float*)take(rowBytes);
  float* pooled = (float*)take((size_t)G * HDIM * sizeof(float));
  unsigned short* wBhi = (unsigned short*)take((size_t)STEPS * 64 * 512 * sizeof(unsigned short));
  unsigned short* wBlo = (unsigned short*)take((size_t)STEPS * 64 * 512 * sizeof(unsigned short));
  int* rowptr   = (int*)take((size_t)(N + 1) * sizeof(int));
  int* cursor   = (int*)take((size_t)N * sizeof(int));  // also used as deg
  int* bsum     = (int*)take((size_t)nb256 * sizeof(int));
  int* eidx     = (int*)take((size_t)E * sizeof(int));

  // --- one-time precompute: packed MFMA weight fragments + CSR by dst ---
  {
    const int total = STEPS * 64 * 512;
    k_prep<<<(total + 255) / 256, 256, 0, stream>>>(ggnn_w, w_ih, w_hh, wBhi, wBlo);
  }
  hipMemsetAsync(cursor, 0, (size_t)N * sizeof(int), stream);
  k_hist<<<(E + 255) / 256, 256, 0, stream>>>(dsts, cursor, E);
  k_scan1<<<nb256, 256, 0, stream>>>(cursor, bsum, N);
  k_scan2<<<1, 1024, 0, stream>>>(bsum, nb256);
  k_scan3<<<nb256, 256, 0, stream>>>(cursor, bsum, rowptr, cursor, N);
  k_fill<<<(E + 255) / 256, 256, 0, stream>>>(srcs, dsts, cursor, eidx, E);

  // --- embed ---
  k_embed<<<(N * HDIM + 255) / 256, 256, 0, stream>>>(tokens, emb, xA, N);

  // --- GGNN steps: fused gather + MFMA GRU, ping-pong x ---
  const int fblocks = (N + 31) / 32;  // 32 nodes per block (two 16-node tiles)
  float* xin = xA;
  float* xout = xB;
  for (int s = 0; s < STEPS; ++s) {
    k_fgru<<<fblocks, 512, 0, stream>>>(rowptr, eidx, (const float4*)xin, xin, xout,
                                        wBhi + (size_t)s * 32768,
                                        wBlo + (size_t)s * 32768,
                                        b_ih, b_hh, N);
    float* tmp = xin; xin = xout; xout = tmp;
  }

  k_pool<<<G, 256, 0, stream>>>(xin, batch, pooled, N);
  k_head<<<1, 256, 0, stream>>>(pooled, lin1_w, lin1_b, lout_w, lout_b,
                                (float*)d_out, G);
}

// Round 21
// 282.324 us; speedup vs baseline: 1.5919x; 1.0890x over previous
//
#include <hip/hip_runtime.h>

#define HDIM 64
#define STEPS 3
#define MAXNB 1024  // supports N <= 65536 at 64 nodes/bucket (problem: N=50000)

typedef __attribute__((ext_vector_type(8))) short s16x8;
typedef __attribute__((ext_vector_type(4))) float f32x4;

__device__ __forceinline__ float bf2f(unsigned short u) {
  return __uint_as_float(((unsigned)u) << 16);
}
__device__ __forceinline__ unsigned short f2bf(float f) {
  unsigned u = __float_as_uint(f);
  unsigned r = (u + 0x7FFFu + ((u >> 16) & 1u)) >> 16;  // RNE
  return (unsigned short)r;
}

// ---------------- embed: x[i] = emb[tokens[i]] ----------------
__global__ __launch_bounds__(256) void k_embed(const int* __restrict__ tokens,
                                               const float* __restrict__ emb,
                                               float* __restrict__ x, int n) {
  int i = blockIdx.x * 256 + threadIdx.x;
  if (i < n * HDIM) {
    int node = i >> 6;
    int h = i & 63;
    x[i] = emb[tokens[node] * HDIM + h];
  }
}

// ---------------- one-time prep: packed MFMA B-fragments (bf16 hi/lo) --------
__global__ __launch_bounds__(256) void k_prep(const float* __restrict__ W,
                                              const float* __restrict__ w_ih,
                                              const float* __restrict__ w_hh,
                                              unsigned short* __restrict__ wBhi,
                                              unsigned short* __restrict__ wBlo) {
  int o = blockIdx.x * 256 + threadIdx.x;
  if (o >= STEPS * 64 * 512) return;
  int s = o / 32768;
  int r1 = o & 32767;
  int fid = r1 >> 9;
  int le = r1 & 511;
  int lane = le >> 3, j = le & 7;
  int c2 = fid >> 2, t = fid & 3;
  int sec = c2 >> 2, csub = c2 & 3;        // sec: 0=r 1=z 2=gi_n 3=gh_n
  int ch = csub * 16 + (lane & 15);        // channel 0..63
  int k = t * 32 + (lane >> 4) * 8 + j;    // 0..127
  float val = 0.f;
  if (k < 64) {
    if (sec < 3) {
      int jcol = sec * 64 + ch;            // w_ih row
      const float4* a4 = (const float4*)(W + (size_t)s * HDIM * HDIM + (size_t)k * HDIM);
      const float4* b4 = (const float4*)(w_ih + (size_t)jcol * HDIM);
      float acc = 0.f;
#pragma unroll
      for (int q = 0; q < HDIM / 4; ++q) {
        float4 a = a4[q];
        float4 b = b4[q];
        acc = fmaf(a.x, b.x, acc);
        acc = fmaf(a.y, b.y, acc);
        acc = fmaf(a.z, b.z, acc);
        acc = fmaf(a.w, b.w, acc);
      }
      val = acc;
    }
  } else {
    int k2 = k - 64;
    if (sec == 0)      val = w_hh[(size_t)(0 + ch) * HDIM + k2];
    else if (sec == 1) val = w_hh[(size_t)(64 + ch) * HDIM + k2];
    else if (sec == 3) val = w_hh[(size_t)(128 + ch) * HDIM + k2];
  }
  unsigned short hi = f2bf(val);
  unsigned short lo = f2bf(val - bf2f(hi));
  wBhi[o] = hi;
  wBlo[o] = lo;
}

// ---------------- bucketed CSR build ----------------
// bucket(d) = d >> 6 (64 nodes/bucket). Replaces node-level hist+fill whose
// random 4B scatters dirtied 64B lines (52MB writeback measured in R20).

// bhist: per-block LDS histogram -> one global add per (block,bucket)
__global__ __launch_bounds__(256) void k_bhist(const int* __restrict__ dsts,
                                               int* __restrict__ bcnt,
                                               int ne, int nb, int chunk) {
  __shared__ int h[MAXNB];
  for (int b = threadIdx.x; b < nb; b += 256) h[b] = 0;
  __syncthreads();
  int base = blockIdx.x * chunk;
  int end = base + chunk; if (end > ne) end = ne;
  for (int e = base + threadIdx.x; e < end; e += 256) {
    atomicAdd(&h[dsts[e] >> 6], 1);
  }
  __syncthreads();
  for (int b = threadIdx.x; b < nb; b += 256) {
    int v = h[b];
    if (v > 0) atomicAdd(&bcnt[b], v);
  }
}

// bscan: one block scans bucket counts -> bbase, bcur; writes rowptr[n]=E
__global__ __launch_bounds__(1024) void k_bscan(const int* __restrict__ bcnt,
                                                int* __restrict__ bbase,
                                                int* __restrict__ bcur,
                                                int* __restrict__ rowptr,
                                                int nb, int n, int ne) {
  __shared__ int s[MAXNB];
  const int tid = threadIdx.x;
  int own = (tid < nb) ? bcnt[tid] : 0;
  if (tid < MAXNB) s[tid] = own;
  __syncthreads();
  for (int off = 1; off < MAXNB; off <<= 1) {
    int v = (tid >= off && tid < MAXNB) ? s[tid - off] : 0;
    __syncthreads();
    if (tid < MAXNB) s[tid] += v;
    __syncthreads();
  }
  if (tid < nb) {
    int excl = s[tid] - own;
    bbase[tid] = excl;
    bcur[tid] = excl;
    if (tid == nb - 1) bbase[nb] = excl + own;  // == ne
  }
  if (tid == 0) rowptr[n] = ne;
}

// bscatter: write packed records (src | dst_local<<20) bucket-grouped.
__global__ __launch_bounds__(256) void k_bscatter(const int* __restrict__ srcs,
                                                  const int* __restrict__ dsts,
                                                  int* __restrict__ bcur,
                                                  int* __restrict__ recs,
                                                  int ne, int nb, int chunk) {
  __shared__ int h[MAXNB];
  __shared__ int rsv[MAXNB];
  for (int b = threadIdx.x; b < nb; b += 256) h[b] = 0;
  __syncthreads();
  int base = blockIdx.x * chunk;
  int end = base + chunk; if (end > ne) end = ne;
  for (int e = base + threadIdx.x; e < end; e += 256) {
    atomicAdd(&h[dsts[e] >> 6], 1);
  }
  __syncthreads();
  for (int b = threadIdx.x; b < nb; b += 256) {
    int v = h[b];
    rsv[b] = (v > 0) ? atomicAdd(&bcur[b], v) : 0;
    h[b] = 0;
  }
  __syncthreads();
  for (int e = base + threadIdx.x; e < end; e += 256) {
    int d = dsts[e];
    int b = d >> 6;
    int l = atomicAdd(&h[b], 1);
    recs[rsv[b] + l] = srcs[e] | ((d & 63) << 20);
  }
}

// bcsr: per bucket, local count+scan -> rowptr (coalesced) + eidx (dense 4KB region)
__global__ __launch_bounds__(256) void k_bcsr(const int* __restrict__ bbase,
                                              const int* __restrict__ recs,
                                              int* __restrict__ rowptr,
                                              int* __restrict__ eidx,
                                              int n) {
  __shared__ int cnt[64];
  __shared__ int incl[64];
  const int b = blockIdx.x;
  const int tid = threadIdx.x;
  const int lo = bbase[b], hi = bbase[b + 1];
  if (tid < 64) cnt[tid] = 0;
  __syncthreads();
  for (int e = lo + tid; e < hi; e += 256) {
    atomicAdd(&cnt[(recs[e] >> 20) & 63], 1);
  }
  __syncthreads();
  if (tid < 64) incl[tid] = cnt[tid];
  __syncthreads();
  for (int off = 1; off < 64; off <<= 1) {
    int v = (tid < 64 && tid >= off) ? incl[tid - off] : 0;
    __syncthreads();
    if (tid < 64) incl[tid] += v;
    __syncthreads();
  }
  if (tid < 64) {
    int excl = incl[tid] - cnt[tid];
    int node = b * 64 + tid;
    if (node < n) rowptr[node] = lo + excl;
    cnt[tid] = excl;  // becomes cursor
  }
  __syncthreads();
  for (int e = lo + tid; e < hi; e += 256) {
    int rec = recs[e];
    int dl = (rec >> 20) & 63;
    int pos = atomicAdd(&cnt[dl], 1);
    eidx[lo + pos] = rec & 0xFFFFF;
  }
}

// ---------------- FUSED gather + MFMA GRU (unchanged from R20, passed) -------
__global__ __launch_bounds__(512, 2) void k_fgru(const int* __restrict__ rowptr,
                                                 const int* __restrict__ eidx,
                                                 const float4* __restrict__ xin4,
                                                 const float* __restrict__ xin,
                                                 float* __restrict__ xout,
                                                 const unsigned short* __restrict__ wBhi_s,
                                                 const unsigned short* __restrict__ wBlo_s,
                                                 const float* __restrict__ b_ih,
                                                 const float* __restrict__ b_hh,
                                                 int n) {
  __shared__ unsigned short Ahi[2][16][136];
  __shared__ unsigned short Alo[2][16][136];

  const int lane = threadIdx.x & 63;
  const int wid = threadIdx.x >> 6;   // 0..7
  const int tile = wid >> 2;          // 0..1
  const int csub = wid & 3;           // 0..3
  const int node_base = blockIdx.x * 32 + tile * 16;

  const int grp = lane >> 4;          // edge stream 0..3
  const int cl = lane & 15;           // float4 channel chunk

#pragma unroll
  for (int q = 0; q < 4; ++q) {
    int i = csub * 4 + q;
    int node = node_base + i;
    float4 acc = make_float4(0.f, 0.f, 0.f, 0.f);
    if (node < n) {
      const int lo = rowptr[node], hi = rowptr[node + 1];
      int e = lo + grp;
      for (; e + 4 < hi; e += 8) {
        int s0 = eidx[e];
        int s1 = eidx[e + 4];
        float4 v0 = xin4[(size_t)s0 * 16 + cl];
        float4 v1 = xin4[(size_t)s1 * 16 + cl];
        acc.x += v0.x + v1.x;
        acc.y += v0.y + v1.y;
        acc.z += v0.z + v1.z;
        acc.w += v0.w + v1.w;
      }
      if (e < hi) {
        int s0 = eidx[e];
        float4 v0 = xin4[(size_t)s0 * 16 + cl];
        acc.x += v0.x; acc.y += v0.y; acc.z += v0.z; acc.w += v0.w;
      }
    }
#pragma unroll
    for (int off = 16; off < 64; off <<= 1) {
      acc.x += __shfl_xor(acc.x, off);
      acc.y += __shfl_xor(acc.y, off);
      acc.z += __shfl_xor(acc.z, off);
      acc.w += __shfl_xor(acc.w, off);
    }
    if (grp == 0) {
      ushort4 hi4, lo4;
      hi4.x = f2bf(acc.x); lo4.x = f2bf(acc.x - bf2f(hi4.x));
      hi4.y = f2bf(acc.y); lo4.y = f2bf(acc.y - bf2f(hi4.y));
      hi4.z = f2bf(acc.z); lo4.z = f2bf(acc.z - bf2f(hi4.z));
      hi4.w = f2bf(acc.w); lo4.w = f2bf(acc.w - bf2f(hi4.w));
      *(ushort4*)&Ahi[tile][i][cl * 4] = hi4;
      *(ushort4*)&Alo[tile][i][cl * 4] = lo4;
    }
    float v = (node < n) ? xin[(size_t)node * HDIM + lane] : 0.f;
    unsigned short hv = f2bf(v);
    Ahi[tile][i][64 + lane] = hv;
    Alo[tile][i][64 + lane] = f2bf(v - bf2f(hv));
  }
  __syncthreads();

  const int row = lane & 15;
  const int kseg = (lane >> 4) * 8;
  s16x8 ah0 = *(const s16x8*)&Ahi[tile][row][0 + kseg];
  s16x8 ah1 = *(const s16x8*)&Ahi[tile][row][32 + kseg];
  s16x8 ah2 = *(const s16x8*)&Ahi[tile][row][64 + kseg];
  s16x8 ah3 = *(const s16x8*)&Ahi[tile][row][96 + kseg];
  s16x8 al0 = *(const s16x8*)&Alo[tile][row][0 + kseg];
  s16x8 al1 = *(const s16x8*)&Alo[tile][row][32 + kseg];
  s16x8 al2 = *(const s16x8*)&Alo[tile][row][64 + kseg];
  s16x8 al3 = *(const s16x8*)&Alo[tile][row][96 + kseg];

  const s16x8* Bh = (const s16x8*)wBhi_s;
  const s16x8* Bl = (const s16x8*)wBlo_s;

  f32x4 accR = {0.f, 0.f, 0.f, 0.f};
  f32x4 accZ = {0.f, 0.f, 0.f, 0.f};
  f32x4 accN = {0.f, 0.f, 0.f, 0.f};
  f32x4 accG = {0.f, 0.f, 0.f, 0.f};

#define MMA3(ACC, AH, AL, FID)                                             \
  {                                                                        \
    s16x8 bh = Bh[(FID) * 64 + lane];                                      \
    s16x8 bl = Bl[(FID) * 64 + lane];                                      \
    ACC = __builtin_amdgcn_mfma_f32_16x16x32_bf16(AH, bh, ACC, 0, 0, 0);   \
    ACC = __builtin_amdgcn_mfma_f32_16x16x32_bf16(AH, bl, ACC, 0, 0, 0);   \
    ACC = __builtin_amdgcn_mfma_f32_16x16x32_bf16(AL, bh, ACC, 0, 0, 0);   \
  }

  {
    const int c2 = 0 + csub;
    MMA3(accR, ah0, al0, c2 * 4 + 0)
    MMA3(accR, ah1, al1, c2 * 4 + 1)
    MMA3(accR, ah2, al2, c2 * 4 + 2)
    MMA3(accR, ah3, al3, c2 * 4 + 3)
  }
  {
    const int c2 = 4 + csub;
    MMA3(accZ, ah0, al0, c2 * 4 + 0)
    MMA3(accZ, ah1, al1, c2 * 4 + 1)
    MMA3(accZ, ah2, al2, c2 * 4 + 2)
    MMA3(accZ, ah3, al3, c2 * 4 + 3)
  }
  {
    const int c2 = 8 + csub;
    MMA3(accN, ah0, al0, c2 * 4 + 0)
    MMA3(accN, ah1, al1, c2 * 4 + 1)
  }
  {
    const int c2 = 12 + csub;
    MMA3(accG, ah2, al2, c2 * 4 + 2)
    MMA3(accG, ah3, al3, c2 * 4 + 3)
  }
#undef MMA3

  const int ch = csub * 16 + (lane & 15);
  const float Br = b_ih[ch] + b_hh[ch];
  const float Bz = b_ih[64 + ch] + b_hh[64 + ch];
  const float Bin = b_ih[128 + ch];
  const float Bhn = b_hh[128 + ch];

#pragma unroll
  for (int reg = 0; reg < 4; ++reg) {
    int i = (lane >> 4) * 4 + reg;
    int node = node_base + i;
    if (node < n) {
      float r = 1.f / (1.f + __expf(-(accR[reg] + Br)));
      float z = 1.f / (1.f + __expf(-(accZ[reg] + Bz)));
      float nn = tanhf((accN[reg] + Bin) + r * (accG[reg] + Bhn));
      float hold = xin[(size_t)node * HDIM + ch];
      xout[(size_t)node * HDIM + ch] = (1.f - z) * nn + z * hold;
    }
  }
}

// ---------------- per-graph mean pool of relu(x); batch sorted ----------------
__device__ __forceinline__ int lower_bound_i(const int* __restrict__ a, int n, int v) {
  int lo = 0, hi = n;
  while (lo < hi) {
    int mid = (lo + hi) >> 1;
    if (a[mid] < v) lo = mid + 1; else hi = mid;
  }
  return lo;
}

__global__ __launch_bounds__(256) void k_pool(const float* __restrict__ x,
                                              const int* __restrict__ batch,
                                              float* __restrict__ pooled,
                                              int n) {
  int g = blockIdx.x;
  int lo = lower_bound_i(batch, n, g);
  int hi = lower_bound_i(batch, n, g + 1);
  const int lane = threadIdx.x & 63;
  const int w = threadIdx.x >> 6;  // 0..3
  float acc = 0.f;
  for (int i = lo + w; i < hi; i += 4) {
    acc += fmaxf(x[i * HDIM + lane], 0.f);
  }
  __shared__ float red[4][HDIM];
  red[w][lane] = acc;
  __syncthreads();
  if (w == 0) {
    float s = red[0][lane] + red[1][lane] + red[2][lane] + red[3][lane];
    float cnt = (float)(hi - lo);
    pooled[g * HDIM + lane] = s / fmaxf(cnt, 1.f);
  }
}

// ---------------- head ----------------
__global__ __launch_bounds__(256) void k_head(const float* __restrict__ pooled,
                                              const float* __restrict__ lin1_w,
                                              const float* __restrict__ lin1_b,
                                              const float* __restrict__ lout_w,
                                              const float* __restrict__ lout_b,
                                              float* __restrict__ out, int G) {
  __shared__ float P[128 * HDIM];
  __shared__ float W1T[HDIM * HDIM];
  __shared__ float H1[128 * HDIM];
  for (int t = threadIdx.x; t < G * HDIM; t += 256) P[t] = pooled[t];
  for (int t = threadIdx.x; t < HDIM * HDIM; t += 256) {
    int j = t & 63, k = t >> 6;
    W1T[k * HDIM + j] = lin1_w[j * HDIM + k];
  }
  __syncthreads();
  for (int idx = threadIdx.x; idx < G * HDIM; idx += 256) {
    int g = idx >> 6, j = idx & 63;
    float acc = lin1_b[j];
#pragma unroll
    for (int k = 0; k < HDIM; ++k) acc = fmaf(P[g * HDIM + k], W1T[k * HDIM + j], acc);
    H1[idx] = fmaxf(acc, 0.f);
  }
  __syncthreads();
  for (int idx = threadIdx.x; idx < G * 2; idx += 256) {
    int g = idx >> 1, c = idx & 1;
    float acc = lout_b[c];
#pragma unroll
    for (int j = 0; j < HDIM; ++j) acc = fmaf(H1[g * HDIM + j], lout_w[c * HDIM + j], acc);
    out[idx] = acc;
  }
}

extern "C" void kernel_launch(void* const* d_in, const int* in_sizes, int n_in,
                              void* d_out, int out_size, void* d_ws, size_t ws_size,
                              hipStream_t stream) {
  const int* tokens   = (const int*)d_in[0];
  const int* edge_idx = (const int*)d_in[1];
  const int* batch    = (const int*)d_in[2];
  const float* emb    = (const float*)d_in[3];
  const float* ggnn_w = (const float*)d_in[4];
  const float* w_ih   = (const float*)d_in[5];
  const float* w_hh   = (const float*)d_in[6];
  const float* b_ih   = (const float*)d_in[7];
  const float* b_hh   = (const float*)d_in[8];
  const float* lin1_w = (const float*)d_in[9];
  const float* lin1_b = (const float*)d_in[10];
  const float* lout_w = (const float*)d_in[11];
  const float* lout_b = (const float*)d_in[12];

  const int N = in_sizes[0];
  const int E = in_sizes[1] / 2;
  const int G = out_size / 2;

  const int* srcs = edge_idx;
  const int* dsts = edge_idx + E;

  char* ws = (char*)d_ws;
  size_t off = 0;
  auto take = [&](size_t nbytes) -> char* {
    char* p = ws + off;
    off += (nbytes + 255) & ~(size_t)255;
    return p;
  };
  size_t rowBytes = (size_t)N * HDIM * sizeof(float);
  const int NB = (N + 63) / 64;  // <= MAXNB for N <= 65536
  float* xA     = (float*)take(rowBytes);
  float* xB     = (float*)take(rowBytes);
  float* pooled = (float*)take((size_t)G * HDIM * sizeof(float));
  unsigned short* wBhi = (unsigned short*)take((size_t)STEPS * 64 * 512 * sizeof(unsigned short));
  unsigned short* wBlo = (unsigned short*)take((size_t)STEPS * 64 * 512 * sizeof(unsigned short));
  int* rowptr   = (int*)take((size_t)(N + 1) * sizeof(int));
  int* bcnt     = (int*)take((size_t)NB * sizeof(int));
  int* bbase    = (int*)take((size_t)(NB + 1) * sizeof(int));
  int* bcur     = (int*)take((size_t)NB * sizeof(int));
  int* recs     = (int*)take((size_t)E * sizeof(int));
  int* eidx     = (int*)take((size_t)E * sizeof(int));

  // --- one-time precompute: packed MFMA weight fragments ---
  {
    const int total = STEPS * 64 * 512;
    k_prep<<<(total + 255) / 256, 256, 0, stream>>>(ggnn_w, w_ih, w_hh, wBhi, wBlo);
  }

  // --- bucketed CSR build ---
  const int CHUNK = 16384;
  const int cblocks = (E + CHUNK - 1) / CHUNK;
  hipMemsetAsync(bcnt, 0, (size_t)NB * sizeof(int), stream);
  k_bhist<<<cblocks, 256, 0, stream>>>(dsts, bcnt, E, NB, CHUNK);
  k_bscan<<<1, 1024, 0, stream>>>(bcnt, bbase, bcur, rowptr, NB, N, E);
  k_bscatter<<<cblocks, 256, 0, stream>>>(srcs, dsts, bcur, recs, E, NB, CHUNK);
  k_bcsr<<<NB, 256, 0, stream>>>(bbase, recs, rowptr, eidx, N);

  // --- embed ---
  k_embed<<<(N * HDIM + 255) / 256, 256, 0, stream>>>(tokens, emb, xA, N);

  // --- GGNN steps: fused gather + MFMA GRU, ping-pong x ---
  const int fblocks = (N + 31) / 32;
  float* xin = xA;
  float* xout = xB;
  for (int s = 0; s < STEPS; ++s) {
    k_fgru<<<fblocks, 512, 0, stream>>>(rowptr, eidx, (const float4*)xin, xin, xout,
                                        wBhi + (size_t)s * 32768,
                                        wBlo + (size_t)s * 32768,
                                        b_ih, b_hh, N);
    float* tmp = xin; xin = xout; xout = tmp;
  }

  k_pool<<<G, 256, 0, stream>>>(xin, batch, pooled, N);
  k_head<<<1, 256, 0, stream>>>(pooled, lin1_w, lin1_b, lout_w, lout_b,
                                (float*)d_out, G);
}

// Round 22
// 248.172 us; speedup vs baseline: 1.8110x; 1.1376x over previous
//
#include <hip/hip_runtime.h>

#define HDIM 64
#define STEPS 3
#define MAXNB 1024  // supports N <= 65536 at 64 nodes/bucket (problem: N=50000)

typedef __attribute__((ext_vector_type(8))) short s16x8;
typedef __attribute__((ext_vector_type(4))) float f32x4;

__device__ __forceinline__ float bf2f(unsigned short u) {
  return __uint_as_float(((unsigned)u) << 16);
}
__device__ __forceinline__ unsigned short f2bf(float f) {
  unsigned u = __float_as_uint(f);
  unsigned r = (u + 0x7FFFu + ((u >> 16) & 1u)) >> 16;  // RNE
  return (unsigned short)r;
}

// ---------------- embed: x[i] = emb[tokens[i]] ----------------
__global__ __launch_bounds__(256) void k_embed(const int* __restrict__ tokens,
                                               const float* __restrict__ emb,
                                               float* __restrict__ x, int n) {
  int i = blockIdx.x * 256 + threadIdx.x;
  if (i < n * HDIM) {
    int node = i >> 6;
    int h = i & 63;
    x[i] = emb[tokens[node] * HDIM + h];
  }
}

// ---------------- one-time prep: packed MFMA B-fragments (bf16 hi/lo) --------
__global__ __launch_bounds__(256) void k_prep(const float* __restrict__ W,
                                              const float* __restrict__ w_ih,
                                              const float* __restrict__ w_hh,
                                              unsigned short* __restrict__ wBhi,
                                              unsigned short* __restrict__ wBlo) {
  int o = blockIdx.x * 256 + threadIdx.x;
  if (o >= STEPS * 64 * 512) return;
  int s = o / 32768;
  int r1 = o & 32767;
  int fid = r1 >> 9;
  int le = r1 & 511;
  int lane = le >> 3, j = le & 7;
  int c2 = fid >> 2, t = fid & 3;
  int sec = c2 >> 2, csub = c2 & 3;        // sec: 0=r 1=z 2=gi_n 3=gh_n
  int ch = csub * 16 + (lane & 15);        // channel 0..63
  int k = t * 32 + (lane >> 4) * 8 + j;    // 0..127
  float val = 0.f;
  if (k < 64) {
    if (sec < 3) {
      int jcol = sec * 64 + ch;            // w_ih row
      const float4* a4 = (const float4*)(W + (size_t)s * HDIM * HDIM + (size_t)k * HDIM);
      const float4* b4 = (const float4*)(w_ih + (size_t)jcol * HDIM);
      float acc = 0.f;
#pragma unroll
      for (int q = 0; q < HDIM / 4; ++q) {
        float4 a = a4[q];
        float4 b = b4[q];
        acc = fmaf(a.x, b.x, acc);
        acc = fmaf(a.y, b.y, acc);
        acc = fmaf(a.z, b.z, acc);
        acc = fmaf(a.w, b.w, acc);
      }
      val = acc;
    }
  } else {
    int k2 = k - 64;
    if (sec == 0)      val = w_hh[(size_t)(0 + ch) * HDIM + k2];
    else if (sec == 1) val = w_hh[(size_t)(64 + ch) * HDIM + k2];
    else if (sec == 3) val = w_hh[(size_t)(128 + ch) * HDIM + k2];
  }
  unsigned short hi = f2bf(val);
  unsigned short lo = f2bf(val - bf2f(hi));
  wBhi[o] = hi;
  wBlo[o] = lo;
}

// ---------------- bucketed CSR build ----------------
// bucket(d) = d >> 6 (64 nodes/bucket). R21 lesson: CHUNK=16384 gave only 49
// blocks (1.9% occupancy, 72us). CHUNK=4096 -> 196 blocks, 4x parallelism;
// per-bucket write runs shrink 21->5 edges (writeback ~12MB, cheap at ~1TB/s).

__global__ __launch_bounds__(256) void k_bhist(const int* __restrict__ dsts,
                                               int* __restrict__ bcnt,
                                               int ne, int nb, int chunk) {
  __shared__ int h[MAXNB];
  for (int b = threadIdx.x; b < nb; b += 256) h[b] = 0;
  __syncthreads();
  int base = blockIdx.x * chunk;
  int end = base + chunk; if (end > ne) end = ne;
  for (int e = base + threadIdx.x; e < end; e += 256) {
    atomicAdd(&h[dsts[e] >> 6], 1);
  }
  __syncthreads();
  for (int b = threadIdx.x; b < nb; b += 256) {
    int v = h[b];
    if (v > 0) atomicAdd(&bcnt[b], v);
  }
}

__global__ __launch_bounds__(1024) void k_bscan(const int* __restrict__ bcnt,
                                                int* __restrict__ bbase,
                                                int* __restrict__ bcur,
                                                int* __restrict__ rowptr,
                                                int nb, int n, int ne) {
  __shared__ int s[MAXNB];
  const int tid = threadIdx.x;
  int own = (tid < nb) ? bcnt[tid] : 0;
  if (tid < MAXNB) s[tid] = own;
  __syncthreads();
  for (int off = 1; off < MAXNB; off <<= 1) {
    int v = (tid >= off && tid < MAXNB) ? s[tid - off] : 0;
    __syncthreads();
    if (tid < MAXNB) s[tid] += v;
    __syncthreads();
  }
  if (tid < nb) {
    int excl = s[tid] - own;
    bbase[tid] = excl;
    bcur[tid] = excl;
    if (tid == nb - 1) bbase[nb] = excl + own;  // == ne
  }
  if (tid == 0) rowptr[n] = ne;
}

__global__ __launch_bounds__(256) void k_bscatter(const int* __restrict__ srcs,
                                                  const int* __restrict__ dsts,
                                                  int* __restrict__ bcur,
                                                  int* __restrict__ recs,
                                                  int ne, int nb, int chunk) {
  __shared__ int h[MAXNB];
  __shared__ int rsv[MAXNB];
  for (int b = threadIdx.x; b < nb; b += 256) h[b] = 0;
  __syncthreads();
  int base = blockIdx.x * chunk;
  int end = base + chunk; if (end > ne) end = ne;
  for (int e = base + threadIdx.x; e < end; e += 256) {
    atomicAdd(&h[dsts[e] >> 6], 1);
  }
  __syncthreads();
  for (int b = threadIdx.x; b < nb; b += 256) {
    int v = h[b];
    rsv[b] = (v > 0) ? atomicAdd(&bcur[b], v) : 0;
    h[b] = 0;
  }
  __syncthreads();
  for (int e = base + threadIdx.x; e < end; e += 256) {
    int d = dsts[e];
    int b = d >> 6;
    int l = atomicAdd(&h[b], 1);
    recs[rsv[b] + l] = srcs[e] | ((d & 63) << 20);
  }
}

__global__ __launch_bounds__(256) void k_bcsr(const int* __restrict__ bbase,
                                              const int* __restrict__ recs,
                                              int* __restrict__ rowptr,
                                              int* __restrict__ eidx,
                                              int n) {
  __shared__ int cnt[64];
  __shared__ int incl[64];
  const int b = blockIdx.x;
  const int tid = threadIdx.x;
  const int lo = bbase[b], hi = bbase[b + 1];
  if (tid < 64) cnt[tid] = 0;
  __syncthreads();
  for (int e = lo + tid; e < hi; e += 256) {
    atomicAdd(&cnt[(recs[e] >> 20) & 63], 1);
  }
  __syncthreads();
  if (tid < 64) incl[tid] = cnt[tid];
  __syncthreads();
  for (int off = 1; off < 64; off <<= 1) {
    int v = (tid < 64 && tid >= off) ? incl[tid - off] : 0;
    __syncthreads();
    if (tid < 64) incl[tid] += v;
    __syncthreads();
  }
  if (tid < 64) {
    int excl = incl[tid] - cnt[tid];
    int node = b * 64 + tid;
    if (node < n) rowptr[node] = lo + excl;
    cnt[tid] = excl;  // becomes cursor
  }
  __syncthreads();
  for (int e = lo + tid; e < hi; e += 256) {
    int rec = recs[e];
    int dl = (rec >> 20) & 63;
    int pos = atomicAdd(&cnt[dl], 1);
    eidx[lo + pos] = rec & 0xFFFFF;
  }
}

// ---------------- FUSED gather + MFMA GRU (unchanged from R20/R21, passed) ---
__global__ __launch_bounds__(512, 2) void k_fgru(const int* __restrict__ rowptr,
                                                 const int* __restrict__ eidx,
                                                 const float4* __restrict__ xin4,
                                                 const float* __restrict__ xin,
                                                 float* __restrict__ xout,
                                                 const unsigned short* __restrict__ wBhi_s,
                                                 const unsigned short* __restrict__ wBlo_s,
                                                 const float* __restrict__ b_ih,
                                                 const float* __restrict__ b_hh,
                                                 int n) {
  __shared__ unsigned short Ahi[2][16][136];
  __shared__ unsigned short Alo[2][16][136];

  const int lane = threadIdx.x & 63;
  const int wid = threadIdx.x >> 6;   // 0..7
  const int tile = wid >> 2;          // 0..1
  const int csub = wid & 3;           // 0..3
  const int node_base = blockIdx.x * 32 + tile * 16;

  const int grp = lane >> 4;          // edge stream 0..3
  const int cl = lane & 15;           // float4 channel chunk

#pragma unroll
  for (int q = 0; q < 4; ++q) {
    int i = csub * 4 + q;
    int node = node_base + i;
    float4 acc = make_float4(0.f, 0.f, 0.f, 0.f);
    if (node < n) {
      const int lo = rowptr[node], hi = rowptr[node + 1];
      int e = lo + grp;
      for (; e + 4 < hi; e += 8) {
        int s0 = eidx[e];
        int s1 = eidx[e + 4];
        float4 v0 = xin4[(size_t)s0 * 16 + cl];
        float4 v1 = xin4[(size_t)s1 * 16 + cl];
        acc.x += v0.x + v1.x;
        acc.y += v0.y + v1.y;
        acc.z += v0.z + v1.z;
        acc.w += v0.w + v1.w;
      }
      if (e < hi) {
        int s0 = eidx[e];
        float4 v0 = xin4[(size_t)s0 * 16 + cl];
        acc.x += v0.x; acc.y += v0.y; acc.z += v0.z; acc.w += v0.w;
      }
    }
#pragma unroll
    for (int off = 16; off < 64; off <<= 1) {
      acc.x += __shfl_xor(acc.x, off);
      acc.y += __shfl_xor(acc.y, off);
      acc.z += __shfl_xor(acc.z, off);
      acc.w += __shfl_xor(acc.w, off);
    }
    if (grp == 0) {
      ushort4 hi4, lo4;
      hi4.x = f2bf(acc.x); lo4.x = f2bf(acc.x - bf2f(hi4.x));
      hi4.y = f2bf(acc.y); lo4.y = f2bf(acc.y - bf2f(hi4.y));
      hi4.z = f2bf(acc.z); lo4.z = f2bf(acc.z - bf2f(hi4.z));
      hi4.w = f2bf(acc.w); lo4.w = f2bf(acc.w - bf2f(hi4.w));
      *(ushort4*)&Ahi[tile][i][cl * 4] = hi4;
      *(ushort4*)&Alo[tile][i][cl * 4] = lo4;
    }
    float v = (node < n) ? xin[(size_t)node * HDIM + lane] : 0.f;
    unsigned short hv = f2bf(v);
    Ahi[tile][i][64 + lane] = hv;
    Alo[tile][i][64 + lane] = f2bf(v - bf2f(hv));
  }
  __syncthreads();

  const int row = lane & 15;
  const int kseg = (lane >> 4) * 8;
  s16x8 ah0 = *(const s16x8*)&Ahi[tile][row][0 + kseg];
  s16x8 ah1 = *(const s16x8*)&Ahi[tile][row][32 + kseg];
  s16x8 ah2 = *(const s16x8*)&Ahi[tile][row][64 + kseg];
  s16x8 ah3 = *(const s16x8*)&Ahi[tile][row][96 + kseg];
  s16x8 al0 = *(const s16x8*)&Alo[tile][row][0 + kseg];
  s16x8 al1 = *(const s16x8*)&Alo[tile][row][32 + kseg];
  s16x8 al2 = *(const s16x8*)&Alo[tile][row][64 + kseg];
  s16x8 al3 = *(const s16x8*)&Alo[tile][row][96 + kseg];

  const s16x8* Bh = (const s16x8*)wBhi_s;
  const s16x8* Bl = (const s16x8*)wBlo_s;

  f32x4 accR = {0.f, 0.f, 0.f, 0.f};
  f32x4 accZ = {0.f, 0.f, 0.f, 0.f};
  f32x4 accN = {0.f, 0.f, 0.f, 0.f};
  f32x4 accG = {0.f, 0.f, 0.f, 0.f};

#define MMA3(ACC, AH, AL, FID)                                             \
  {                                                                        \
    s16x8 bh = Bh[(FID) * 64 + lane];                                      \
    s16x8 bl = Bl[(FID) * 64 + lane];                                      \
    ACC = __builtin_amdgcn_mfma_f32_16x16x32_bf16(AH, bh, ACC, 0, 0, 0);   \
    ACC = __builtin_amdgcn_mfma_f32_16x16x32_bf16(AH, bl, ACC, 0, 0, 0);   \
    ACC = __builtin_amdgcn_mfma_f32_16x16x32_bf16(AL, bh, ACC, 0, 0, 0);   \
  }

  {
    const int c2 = 0 + csub;
    MMA3(accR, ah0, al0, c2 * 4 + 0)
    MMA3(accR, ah1, al1, c2 * 4 + 1)
    MMA3(accR, ah2, al2, c2 * 4 + 2)
    MMA3(accR, ah3, al3, c2 * 4 + 3)
  }
  {
    const int c2 = 4 + csub;
    MMA3(accZ, ah0, al0, c2 * 4 + 0)
    MMA3(accZ, ah1, al1, c2 * 4 + 1)
    MMA3(accZ, ah2, al2, c2 * 4 + 2)
    MMA3(accZ, ah3, al3, c2 * 4 + 3)
  }
  {
    const int c2 = 8 + csub;
    MMA3(accN, ah0, al0, c2 * 4 + 0)
    MMA3(accN, ah1, al1, c2 * 4 + 1)
  }
  {
    const int c2 = 12 + csub;
    MMA3(accG, ah2, al2, c2 * 4 + 2)
    MMA3(accG, ah3, al3, c2 * 4 + 3)
  }
#undef MMA3

  const int ch = csub * 16 + (lane & 15);
  const float Br = b_ih[ch] + b_hh[ch];
  const float Bz = b_ih[64 + ch] + b_hh[64 + ch];
  const float Bin = b_ih[128 + ch];
  const float Bhn = b_hh[128 + ch];

#pragma unroll
  for (int reg = 0; reg < 4; ++reg) {
    int i = (lane >> 4) * 4 + reg;
    int node = node_base + i;
    if (node < n) {
      float r = 1.f / (1.f + __expf(-(accR[reg] + Br)));
      float z = 1.f / (1.f + __expf(-(accZ[reg] + Bz)));
      float nn = tanhf((accN[reg] + Bin) + r * (accG[reg] + Bhn));
      float hold = xin[(size_t)node * HDIM + ch];
      xout[(size_t)node * HDIM + ch] = (1.f - z) * nn + z * hold;
    }
  }
}

// ---------------- per-graph mean pool of relu(x); batch sorted ----------------
__device__ __forceinline__ int lower_bound_i(const int* __restrict__ a, int n, int v) {
  int lo = 0, hi = n;
  while (lo < hi) {
    int mid = (lo + hi) >> 1;
    if (a[mid] < v) lo = mid + 1; else hi = mid;
  }
  return lo;
}

__global__ __launch_bounds__(256) void k_pool(const float* __restrict__ x,
                                              const int* __restrict__ batch,
                                              float* __restrict__ pooled,
                                              int n) {
  int g = blockIdx.x;
  int lo = lower_bound_i(batch, n, g);
  int hi = lower_bound_i(batch, n, g + 1);
  const int lane = threadIdx.x & 63;
  const int w = threadIdx.x >> 6;  // 0..3
  float acc = 0.f;
  for (int i = lo + w; i < hi; i += 4) {
    acc += fmaxf(x[i * HDIM + lane], 0.f);
  }
  __shared__ float red[4][HDIM];
  red[w][lane] = acc;
  __syncthreads();
  if (w == 0) {
    float s = red[0][lane] + red[1][lane] + red[2][lane] + red[3][lane];
    float cnt = (float)(hi - lo);
    pooled[g * HDIM + lane] = s / fmaxf(cnt, 1.f);
  }
}

// ---------------- head ----------------
__global__ __launch_bounds__(256) void k_head(const float* __restrict__ pooled,
                                              const float* __restrict__ lin1_w,
                                              const float* __restrict__ lin1_b,
                                              const float* __restrict__ lout_w,
                                              const float* __restrict__ lout_b,
                                              float* __restrict__ out, int G) {
  __shared__ float P[128 * HDIM];
  __shared__ float W1T[HDIM * HDIM];
  __shared__ float H1[128 * HDIM];
  for (int t = threadIdx.x; t < G * HDIM; t += 256) P[t] = pooled[t];
  for (int t = threadIdx.x; t < HDIM * HDIM; t += 256) {
    int j = t & 63, k = t >> 6;
    W1T[k * HDIM + j] = lin1_w[j * HDIM + k];
  }
  __syncthreads();
  for (int idx = threadIdx.x; idx < G * HDIM; idx += 256) {
    int g = idx >> 6, j = idx & 63;
    float acc = lin1_b[j];
#pragma unroll
    for (int k = 0; k < HDIM; ++k) acc = fmaf(P[g * HDIM + k], W1T[k * HDIM + j], acc);
    H1[idx] = fmaxf(acc, 0.f);
  }
  __syncthreads();
  for (int idx = threadIdx.x; idx < G * 2; idx += 256) {
    int g = idx >> 1, c = idx & 1;
    float acc = lout_b[c];
#pragma unroll
    for (int j = 0; j < HDIM; ++j) acc = fmaf(H1[g * HDIM + j], lout_w[c * HDIM + j], acc);
    out[idx] = acc;
  }
}

extern "C" void kernel_launch(void* const* d_in, const int* in_sizes, int n_in,
                              void* d_out, int out_size, void* d_ws, size_t ws_size,
                              hipStream_t stream) {
  const int* tokens   = (const int*)d_in[0];
  const int* edge_idx = (const int*)d_in[1];
  const int* batch    = (const int*)d_in[2];
  const float* emb    = (const float*)d_in[3];
  const float* ggnn_w = (const float*)d_in[4];
  const float* w_ih   = (const float*)d_in[5];
  const float* w_hh   = (const float*)d_in[6];
  const float* b_ih   = (const float*)d_in[7];
  const float* b_hh   = (const float*)d_in[8];
  const float* lin1_w = (const float*)d_in[9];
  const float* lin1_b = (const float*)d_in[10];
  const float* lout_w = (const float*)d_in[11];
  const float* lout_b = (const float*)d_in[12];

  const int N = in_sizes[0];
  const int E = in_sizes[1] / 2;
  const int G = out_size / 2;

  const int* srcs = edge_idx;
  const int* dsts = edge_idx + E;

  char* ws = (char*)d_ws;
  size_t off = 0;
  auto take = [&](size_t nbytes) -> char* {
    char* p = ws + off;
    off += (nbytes + 255) & ~(size_t)255;
    return p;
  };
  size_t rowBytes = (size_t)N * HDIM * sizeof(float);
  const int NB = (N + 63) / 64;  // <= MAXNB for N <= 65536
  float* xA     = (float*)take(rowBytes);
  float* xB     = (float*)take(rowBytes);
  float* pooled = (float*)take((size_t)G * HDIM * sizeof(float));
  unsigned short* wBhi = (unsigned short*)take((size_t)STEPS * 64 * 512 * sizeof(unsigned short));
  unsigned short* wBlo = (unsigned short*)take((size_t)STEPS * 64 * 512 * sizeof(unsigned short));
  int* rowptr   = (int*)take((size_t)(N + 1) * sizeof(int));
  int* bcnt     = (int*)take((size_t)NB * sizeof(int));
  int* bbase    = (int*)take((size_t)(NB + 1) * sizeof(int));
  int* bcur     = (int*)take((size_t)NB * sizeof(int));
  int* recs     = (int*)take((size_t)E * sizeof(int));
  int* eidx     = (int*)take((size_t)E * sizeof(int));

  // --- one-time precompute: packed MFMA weight fragments ---
  {
    const int total = STEPS * 64 * 512;
    k_prep<<<(total + 255) / 256, 256, 0, stream>>>(ggnn_w, w_ih, w_hh, wBhi, wBlo);
  }

  // --- bucketed CSR build (CHUNK=4096 -> ~196 blocks, R21 was 49 @ 1.9% occ) ---
  const int CHUNK = 4096;
  const int cblocks = (E + CHUNK - 1) / CHUNK;
  hipMemsetAsync(bcnt, 0, (size_t)NB * sizeof(int), stream);
  k_bhist<<<cblocks, 256, 0, stream>>>(dsts, bcnt, E, NB, CHUNK);
  k_bscan<<<1, 1024, 0, stream>>>(bcnt, bbase, bcur, rowptr, NB, N, E);
  k_bscatter<<<cblocks, 256, 0, stream>>>(srcs, dsts, bcur, recs, E, NB, CHUNK);
  k_bcsr<<<NB, 256, 0, stream>>>(bbase, recs, rowptr, eidx, N);

  // --- embed ---
  k_embed<<<(N * HDIM + 255) / 256, 256, 0, stream>>>(tokens, emb, xA, N);

  // --- GGNN steps: fused gather + MFMA GRU, ping-pong x ---
  const int fblocks = (N + 31) / 32;
  float* xin = xA;
  float* xout = xB;
  for (int s = 0; s < STEPS; ++s) {
    k_fgru<<<fblocks, 512, 0, stream>>>(rowptr, eidx, (const float4*)xin, xin, xout,
                                        wBhi + (size_t)s * 32768,
                                        wBlo + (size_t)s * 32768,
                                        b_ih, b_hh, N);
    float* tmp = xin; xin = xout; xout = tmp;
  }

  k_pool<<<G, 256, 0, stream>>>(xin, batch, pooled, N);
  k_head<<<1, 256, 0, stream>>>(pooled, lin1_w, lin1_b, lout_w, lout_b,
                                (float*)d_out, G);
}

// Round 23
// 236.972 us; speedup vs baseline: 1.8966x; 1.0473x over previous
//
#include <hip/hip_runtime.h>

#define HDIM 64
#define STEPS 3
#define MAXNB 1024  // supports N <= 65536 at 64 nodes/bucket (problem: N=50000)

typedef __attribute__((ext_vector_type(8))) short s16x8;
typedef __attribute__((ext_vector_type(4))) float f32x4;

__device__ __forceinline__ float bf2f(unsigned short u) {
  return __uint_as_float(((unsigned)u) << 16);
}
__device__ __forceinline__ unsigned short f2bf(float f) {
  unsigned u = __float_as_uint(f);
  unsigned r = (u + 0x7FFFu + ((u >> 16) & 1u)) >> 16;  // RNE
  return (unsigned short)r;
}

// ---------------- embed: x[i] = emb[tokens[i]] (fp32 + bf16 mirror) ----------
__global__ __launch_bounds__(256) void k_embed(const int* __restrict__ tokens,
                                               const float* __restrict__ emb,
                                               float* __restrict__ x,
                                               unsigned short* __restrict__ xbf, int n) {
  int i = blockIdx.x * 256 + threadIdx.x;
  if (i < n * HDIM) {
    int node = i >> 6;
    int h = i & 63;
    float v = emb[tokens[node] * HDIM + h];
    x[i] = v;
    xbf[i] = f2bf(v);
  }
}

// ---------------- one-time prep: packed MFMA B-fragments (bf16 hi/lo) --------
__global__ __launch_bounds__(256) void k_prep(const float* __restrict__ W,
                                              const float* __restrict__ w_ih,
                                              const float* __restrict__ w_hh,
                                              unsigned short* __restrict__ wBhi,
                                              unsigned short* __restrict__ wBlo) {
  int o = blockIdx.x * 256 + threadIdx.x;
  if (o >= STEPS * 64 * 512) return;
  int s = o / 32768;
  int r1 = o & 32767;
  int fid = r1 >> 9;
  int le = r1 & 511;
  int lane = le >> 3, j = le & 7;
  int c2 = fid >> 2, t = fid & 3;
  int sec = c2 >> 2, csub = c2 & 3;        // sec: 0=r 1=z 2=gi_n 3=gh_n
  int ch = csub * 16 + (lane & 15);        // channel 0..63
  int k = t * 32 + (lane >> 4) * 8 + j;    // 0..127
  float val = 0.f;
  if (k < 64) {
    if (sec < 3) {
      int jcol = sec * 64 + ch;            // w_ih row
      const float4* a4 = (const float4*)(W + (size_t)s * HDIM * HDIM + (size_t)k * HDIM);
      const float4* b4 = (const float4*)(w_ih + (size_t)jcol * HDIM);
      float acc = 0.f;
#pragma unroll
      for (int q = 0; q < HDIM / 4; ++q) {
        float4 a = a4[q];
        float4 b = b4[q];
        acc = fmaf(a.x, b.x, acc);
        acc = fmaf(a.y, b.y, acc);
        acc = fmaf(a.z, b.z, acc);
        acc = fmaf(a.w, b.w, acc);
      }
      val = acc;
    }
  } else {
    int k2 = k - 64;
    if (sec == 0)      val = w_hh[(size_t)(0 + ch) * HDIM + k2];
    else if (sec == 1) val = w_hh[(size_t)(64 + ch) * HDIM + k2];
    else if (sec == 3) val = w_hh[(size_t)(128 + ch) * HDIM + k2];
  }
  unsigned short hi = f2bf(val);
  unsigned short lo = f2bf(val - bf2f(hi));
  wBhi[o] = hi;
  wBlo[o] = lo;
}

// ---------------- bucketed CSR build (R22 proven: CHUNK=4096) ----------------
__global__ __launch_bounds__(256) void k_bhist(const int* __restrict__ dsts,
                                               int* __restrict__ bcnt,
                                               int ne, int nb, int chunk) {
  __shared__ int h[MAXNB];
  for (int b = threadIdx.x; b < nb; b += 256) h[b] = 0;
  __syncthreads();
  int base = blockIdx.x * chunk;
  int end = base + chunk; if (end > ne) end = ne;
  for (int e = base + threadIdx.x; e < end; e += 256) {
    atomicAdd(&h[dsts[e] >> 6], 1);
  }
  __syncthreads();
  for (int b = threadIdx.x; b < nb; b += 256) {
    int v = h[b];
    if (v > 0) atomicAdd(&bcnt[b], v);
  }
}

__global__ __launch_bounds__(1024) void k_bscan(const int* __restrict__ bcnt,
                                                int* __restrict__ bbase,
                                                int* __restrict__ bcur,
                                                int* __restrict__ rowptr,
                                                int nb, int n, int ne) {
  __shared__ int s[MAXNB];
  const int tid = threadIdx.x;
  int own = (tid < nb) ? bcnt[tid] : 0;
  if (tid < MAXNB) s[tid] = own;
  __syncthreads();
  for (int off = 1; off < MAXNB; off <<= 1) {
    int v = (tid >= off && tid < MAXNB) ? s[tid - off] : 0;
    __syncthreads();
    if (tid < MAXNB) s[tid] += v;
    __syncthreads();
  }
  if (tid < nb) {
    int excl = s[tid] - own;
    bbase[tid] = excl;
    bcur[tid] = excl;
    if (tid == nb - 1) bbase[nb] = excl + own;  // == ne
  }
  if (tid == 0) rowptr[n] = ne;
}

__global__ __launch_bounds__(256) void k_bscatter(const int* __restrict__ srcs,
                                                  const int* __restrict__ dsts,
                                                  int* __restrict__ bcur,
                                                  int* __restrict__ recs,
                                                  int ne, int nb, int chunk) {
  __shared__ int h[MAXNB];
  __shared__ int rsv[MAXNB];
  for (int b = threadIdx.x; b < nb; b += 256) h[b] = 0;
  __syncthreads();
  int base = blockIdx.x * chunk;
  int end = base + chunk; if (end > ne) end = ne;
  for (int e = base + threadIdx.x; e < end; e += 256) {
    atomicAdd(&h[dsts[e] >> 6], 1);
  }
  __syncthreads();
  for (int b = threadIdx.x; b < nb; b += 256) {
    int v = h[b];
    rsv[b] = (v > 0) ? atomicAdd(&bcur[b], v) : 0;
    h[b] = 0;
  }
  __syncthreads();
  for (int e = base + threadIdx.x; e < end; e += 256) {
    int d = dsts[e];
    int b = d >> 6;
    int l = atomicAdd(&h[b], 1);
    recs[rsv[b] + l] = srcs[e] | ((d & 63) << 20);
  }
}

__global__ __launch_bounds__(256) void k_bcsr(const int* __restrict__ bbase,
                                              const int* __restrict__ recs,
                                              int* __restrict__ rowptr,
                                              int* __restrict__ eidx,
                                              int n) {
  __shared__ int cnt[64];
  __shared__ int incl[64];
  const int b = blockIdx.x;
  const int tid = threadIdx.x;
  const int lo = bbase[b], hi = bbase[b + 1];
  if (tid < 64) cnt[tid] = 0;
  __syncthreads();
  for (int e = lo + tid; e < hi; e += 256) {
    atomicAdd(&cnt[(recs[e] >> 20) & 63], 1);
  }
  __syncthreads();
  if (tid < 64) incl[tid] = cnt[tid];
  __syncthreads();
  for (int off = 1; off < 64; off <<= 1) {
    int v = (tid < 64 && tid >= off) ? incl[tid - off] : 0;
    __syncthreads();
    if (tid < 64) incl[tid] += v;
    __syncthreads();
  }
  if (tid < 64) {
    int excl = incl[tid] - cnt[tid];
    int node = b * 64 + tid;
    if (node < n) rowptr[node] = lo + excl;
    cnt[tid] = excl;  // becomes cursor
  }
  __syncthreads();
  for (int e = lo + tid; e < hi; e += 256) {
    int rec = recs[e];
    int dl = (rec >> 20) & 63;
    int pos = atomicAdd(&cnt[dl], 1);
    eidx[lo + pos] = rec & 0xFFFFF;
  }
}

// ---------------- FUSED gather + MFMA GRU ----------------
// R22 structure + bf16 gather mirror (halves the random-gather miss bytes;
// R22 counters show the kernel is byte-bound at ~2TB/s: FETCH 83.6MB / 48us).
// All arithmetic stays fp32; own-row h and epilogue hold use the fp32 buffer;
// epilogue writes fp32 + bf16(RNE) mirrors. Combined error measured 4.9e-4
// in R19 with this exact gather precision (threshold 1.5e-3).
__global__ __launch_bounds__(512, 2) void k_fgru(const int* __restrict__ rowptr,
                                                 const int* __restrict__ eidx,
                                                 const ushort4* __restrict__ xbf4,
                                                 const float* __restrict__ xin,
                                                 float* __restrict__ xout,
                                                 unsigned short* __restrict__ xbf_out,
                                                 const unsigned short* __restrict__ wBhi_s,
                                                 const unsigned short* __restrict__ wBlo_s,
                                                 const float* __restrict__ b_ih,
                                                 const float* __restrict__ b_hh,
                                                 int n) {
  __shared__ unsigned short Ahi[2][16][136];
  __shared__ unsigned short Alo[2][16][136];

  const int lane = threadIdx.x & 63;
  const int wid = threadIdx.x >> 6;   // 0..7
  const int tile = wid >> 2;          // 0..1
  const int csub = wid & 3;           // 0..3
  const int node_base = blockIdx.x * 32 + tile * 16;

  const int grp = lane >> 4;          // edge stream 0..3
  const int cl = lane & 15;           // 4-channel chunk

#pragma unroll
  for (int q = 0; q < 4; ++q) {
    int i = csub * 4 + q;
    int node = node_base + i;
    float4 acc = make_float4(0.f, 0.f, 0.f, 0.f);
    if (node < n) {
      const int lo = rowptr[node], hi = rowptr[node + 1];
      int e = lo + grp;
      for (; e + 4 < hi; e += 8) {
        int s0 = eidx[e];
        int s1 = eidx[e + 4];
        ushort4 u0 = xbf4[(size_t)s0 * 16 + cl];
        ushort4 u1 = xbf4[(size_t)s1 * 16 + cl];
        acc.x += bf2f(u0.x) + bf2f(u1.x);
        acc.y += bf2f(u0.y) + bf2f(u1.y);
        acc.z += bf2f(u0.z) + bf2f(u1.z);
        acc.w += bf2f(u0.w) + bf2f(u1.w);
      }
      if (e < hi) {
        int s0 = eidx[e];
        ushort4 u0 = xbf4[(size_t)s0 * 16 + cl];
        acc.x += bf2f(u0.x); acc.y += bf2f(u0.y);
        acc.z += bf2f(u0.z); acc.w += bf2f(u0.w);
      }
    }
#pragma unroll
    for (int off = 16; off < 64; off <<= 1) {
      acc.x += __shfl_xor(acc.x, off);
      acc.y += __shfl_xor(acc.y, off);
      acc.z += __shfl_xor(acc.z, off);
      acc.w += __shfl_xor(acc.w, off);
    }
    if (grp == 0) {
      ushort4 hi4, lo4;
      hi4.x = f2bf(acc.x); lo4.x = f2bf(acc.x - bf2f(hi4.x));
      hi4.y = f2bf(acc.y); lo4.y = f2bf(acc.y - bf2f(hi4.y));
      hi4.z = f2bf(acc.z); lo4.z = f2bf(acc.z - bf2f(hi4.z));
      hi4.w = f2bf(acc.w); lo4.w = f2bf(acc.w - bf2f(hi4.w));
      *(ushort4*)&Ahi[tile][i][cl * 4] = hi4;
      *(ushort4*)&Alo[tile][i][cl * 4] = lo4;
    }
    float v = (node < n) ? xin[(size_t)node * HDIM + lane] : 0.f;
    unsigned short hv = f2bf(v);
    Ahi[tile][i][64 + lane] = hv;
    Alo[tile][i][64 + lane] = f2bf(v - bf2f(hv));
  }
  __syncthreads();

  const int row = lane & 15;
  const int kseg = (lane >> 4) * 8;
  s16x8 ah0 = *(const s16x8*)&Ahi[tile][row][0 + kseg];
  s16x8 ah1 = *(const s16x8*)&Ahi[tile][row][32 + kseg];
  s16x8 ah2 = *(const s16x8*)&Ahi[tile][row][64 + kseg];
  s16x8 ah3 = *(const s16x8*)&Ahi[tile][row][96 + kseg];
  s16x8 al0 = *(const s16x8*)&Alo[tile][row][0 + kseg];
  s16x8 al1 = *(const s16x8*)&Alo[tile][row][32 + kseg];
  s16x8 al2 = *(const s16x8*)&Alo[tile][row][64 + kseg];
  s16x8 al3 = *(const s16x8*)&Alo[tile][row][96 + kseg];

  const s16x8* Bh = (const s16x8*)wBhi_s;
  const s16x8* Bl = (const s16x8*)wBlo_s;

  f32x4 accR = {0.f, 0.f, 0.f, 0.f};
  f32x4 accZ = {0.f, 0.f, 0.f, 0.f};
  f32x4 accN = {0.f, 0.f, 0.f, 0.f};
  f32x4 accG = {0.f, 0.f, 0.f, 0.f};

#define MMA3(ACC, AH, AL, FID)                                             \
  {                                                                        \
    s16x8 bh = Bh[(FID) * 64 + lane];                                      \
    s16x8 bl = Bl[(FID) * 64 + lane];                                      \
    ACC = __builtin_amdgcn_mfma_f32_16x16x32_bf16(AH, bh, ACC, 0, 0, 0);   \
    ACC = __builtin_amdgcn_mfma_f32_16x16x32_bf16(AH, bl, ACC, 0, 0, 0);   \
    ACC = __builtin_amdgcn_mfma_f32_16x16x32_bf16(AL, bh, ACC, 0, 0, 0);   \
  }

  {
    const int c2 = 0 + csub;
    MMA3(accR, ah0, al0, c2 * 4 + 0)
    MMA3(accR, ah1, al1, c2 * 4 + 1)
    MMA3(accR, ah2, al2, c2 * 4 + 2)
    MMA3(accR, ah3, al3, c2 * 4 + 3)
  }
  {
    const int c2 = 4 + csub;
    MMA3(accZ, ah0, al0, c2 * 4 + 0)
    MMA3(accZ, ah1, al1, c2 * 4 + 1)
    MMA3(accZ, ah2, al2, c2 * 4 + 2)
    MMA3(accZ, ah3, al3, c2 * 4 + 3)
  }
  {
    const int c2 = 8 + csub;
    MMA3(accN, ah0, al0, c2 * 4 + 0)
    MMA3(accN, ah1, al1, c2 * 4 + 1)
  }
  {
    const int c2 = 12 + csub;
    MMA3(accG, ah2, al2, c2 * 4 + 2)
    MMA3(accG, ah3, al3, c2 * 4 + 3)
  }
#undef MMA3

  const int ch = csub * 16 + (lane & 15);
  const float Br = b_ih[ch] + b_hh[ch];
  const float Bz = b_ih[64 + ch] + b_hh[64 + ch];
  const float Bin = b_ih[128 + ch];
  const float Bhn = b_hh[128 + ch];

#pragma unroll
  for (int reg = 0; reg < 4; ++reg) {
    int i = (lane >> 4) * 4 + reg;
    int node = node_base + i;
    if (node < n) {
      float r = 1.f / (1.f + __expf(-(accR[reg] + Br)));
      float z = 1.f / (1.f + __expf(-(accZ[reg] + Bz)));
      float nn = tanhf((accN[reg] + Bin) + r * (accG[reg] + Bhn));
      float hold = xin[(size_t)node * HDIM + ch];
      float val = (1.f - z) * nn + z * hold;
      xout[(size_t)node * HDIM + ch] = val;
      xbf_out[(size_t)node * HDIM + ch] = f2bf(val);
    }
  }
}

// ---------------- per-graph mean pool of relu(x); batch sorted ----------------
__device__ __forceinline__ int lower_bound_i(const int* __restrict__ a, int n, int v) {
  int lo = 0, hi = n;
  while (lo < hi) {
    int mid = (lo + hi) >> 1;
    if (a[mid] < v) lo = mid + 1; else hi = mid;
  }
  return lo;
}

__global__ __launch_bounds__(256) void k_pool(const float* __restrict__ x,
                                              const int* __restrict__ batch,
                                              float* __restrict__ pooled,
                                              int n) {
  int g = blockIdx.x;
  int lo = lower_bound_i(batch, n, g);
  int hi = lower_bound_i(batch, n, g + 1);
  const int lane = threadIdx.x & 63;
  const int w = threadIdx.x >> 6;  // 0..3
  float acc = 0.f;
  for (int i = lo + w; i < hi; i += 4) {
    acc += fmaxf(x[i * HDIM + lane], 0.f);
  }
  __shared__ float red[4][HDIM];
  red[w][lane] = acc;
  __syncthreads();
  if (w == 0) {
    float s = red[0][lane] + red[1][lane] + red[2][lane] + red[3][lane];
    float cnt = (float)(hi - lo);
    pooled[g * HDIM + lane] = s / fmaxf(cnt, 1.f);
  }
}

// ---------------- head ----------------
__global__ __launch_bounds__(256) void k_head(const float* __restrict__ pooled,
                                              const float* __restrict__ lin1_w,
                                              const float* __restrict__ lin1_b,
                                              const float* __restrict__ lout_w,
                                              const float* __restrict__ lout_b,
                                              float* __restrict__ out, int G) {
  __shared__ float P[128 * HDIM];
  __shared__ float W1T[HDIM * HDIM];
  __shared__ float H1[128 * HDIM];
  for (int t = threadIdx.x; t < G * HDIM; t += 256) P[t] = pooled[t];
  for (int t = threadIdx.x; t < HDIM * HDIM; t += 256) {
    int j = t & 63, k = t >> 6;
    W1T[k * HDIM + j] = lin1_w[j * HDIM + k];
  }
  __syncthreads();
  for (int idx = threadIdx.x; idx < G * HDIM; idx += 256) {
    int g = idx >> 6, j = idx & 63;
    float acc = lin1_b[j];
#pragma unroll
    for (int k = 0; k < HDIM; ++k) acc = fmaf(P[g * HDIM + k], W1T[k * HDIM + j], acc);
    H1[idx] = fmaxf(acc, 0.f);
  }
  __syncthreads();
  for (int idx = threadIdx.x; idx < G * 2; idx += 256) {
    int g = idx >> 1, c = idx & 1;
    float acc = lout_b[c];
#pragma unroll
    for (int j = 0; j < HDIM; ++j) acc = fmaf(H1[g * HDIM + j], lout_w[c * HDIM + j], acc);
    out[idx] = acc;
  }
}

extern "C" void kernel_launch(void* const* d_in, const int* in_sizes, int n_in,
                              void* d_out, int out_size, void* d_ws, size_t ws_size,
                              hipStream_t stream) {
  const int* tokens   = (const int*)d_in[0];
  const int* edge_idx = (const int*)d_in[1];
  const int* batch    = (const int*)d_in[2];
  const float* emb    = (const float*)d_in[3];
  const float* ggnn_w = (const float*)d_in[4];
  const float* w_ih   = (const float*)d_in[5];
  const float* w_hh   = (const float*)d_in[6];
  const float* b_ih   = (const float*)d_in[7];
  const float* b_hh   = (const float*)d_in[8];
  const float* lin1_w = (const float*)d_in[9];
  const float* lin1_b = (const float*)d_in[10];
  const float* lout_w = (const float*)d_in[11];
  const float* lout_b = (const float*)d_in[12];

  const int N = in_sizes[0];
  const int E = in_sizes[1] / 2;
  const int G = out_size / 2;

  const int* srcs = edge_idx;
  const int* dsts = edge_idx + E;

  char* ws = (char*)d_ws;
  size_t off = 0;
  auto take = [&](size_t nbytes) -> char* {
    char* p = ws + off;
    off += (nbytes + 255) & ~(size_t)255;
    return p;
  };
  size_t rowBytes = (size_t)N * HDIM * sizeof(float);
  size_t bfBytes  = (size_t)N * HDIM * sizeof(unsigned short);
  const int NB = (N + 63) / 64;  // <= MAXNB for N <= 65536
  float* xA     = (float*)take(rowBytes);
  float* xB     = (float*)take(rowBytes);
  unsigned short* bfA = (unsigned short*)take(bfBytes);
  unsigned short* bfB = (unsigned short*)take(bfBytes);
  float* pooled = (float*)take((size_t)G * HDIM * sizeof(float));
  unsigned short* wBhi = (unsigned short*)take((size_t)STEPS * 64 * 512 * sizeof(unsigned short));
  unsigned short* wBlo = (unsigned short*)take((size_t)STEPS * 64 * 512 * sizeof(unsigned short));
  int* rowptr   = (int*)take((size_t)(N + 1) * sizeof(int));
  int* bcnt     = (int*)take((size_t)NB * sizeof(int));
  int* bbase    = (int*)take((size_t)(NB + 1) * sizeof(int));
  int* bcur     = (int*)take((size_t)NB * sizeof(int));
  int* recs     = (int*)take((size_t)E * sizeof(int));
  int* eidx     = (int*)take((size_t)E * sizeof(int));

  // --- one-time precompute: packed MFMA weight fragments ---
  {
    const int total = STEPS * 64 * 512;
    k_prep<<<(total + 255) / 256, 256, 0, stream>>>(ggnn_w, w_ih, w_hh, wBhi, wBlo);
  }

  // --- bucketed CSR build (CHUNK=4096, proven R22) ---
  const int CHUNK = 4096;
  const int cblocks = (E + CHUNK - 1) / CHUNK;
  hipMemsetAsync(bcnt, 0, (size_t)NB * sizeof(int), stream);
  k_bhist<<<cblocks, 256, 0, stream>>>(dsts, bcnt, E, NB, CHUNK);
  k_bscan<<<1, 1024, 0, stream>>>(bcnt, bbase, bcur, rowptr, NB, N, E);
  k_bscatter<<<cblocks, 256, 0, stream>>>(srcs, dsts, bcur, recs, E, NB, CHUNK);
  k_bcsr<<<NB, 256, 0, stream>>>(bbase, recs, rowptr, eidx, N);

  // --- embed (fp32 + bf16 mirror) ---
  k_embed<<<(N * HDIM + 255) / 256, 256, 0, stream>>>(tokens, emb, xA, bfA, N);

  // --- GGNN steps: fused gather + MFMA GRU, ping-pong x / xbf ---
  const int fblocks = (N + 31) / 32;
  float* xin = xA;
  float* xout = xB;
  unsigned short* bin = bfA;
  unsigned short* bout = bfB;
  for (int s = 0; s < STEPS; ++s) {
    k_fgru<<<fblocks, 512, 0, stream>>>(rowptr, eidx, (const ushort4*)bin, xin, xout,
                                        bout,
                                        wBhi + (size_t)s * 32768,
                                        wBlo + (size_t)s * 32768,
                                        b_ih, b_hh, N);
    float* t1 = xin; xin = xout; xout = t1;
    unsigned short* t2 = bin; bin = bout; bout = t2;
  }

  k_pool<<<G, 256, 0, stream>>>(xin, batch, pooled, N);
  k_head<<<1, 256, 0, stream>>>(pooled, lin1_w, lin1_b, lout_w, lout_b,
                                (float*)d_out, G);
}

// Round 24
// 235.981 us; speedup vs baseline: 1.9046x; 1.0042x over previous
//
#include <hip/hip_runtime.h>

#define HDIM 64
#define STEPS 3
#define MAXNB 1024  // supports N <= 65536 at 64 nodes/bucket (problem: N=50000)

typedef __attribute__((ext_vector_type(8))) short s16x8;
typedef __attribute__((ext_vector_type(4))) float f32x4;

__device__ __forceinline__ float bf2f(unsigned short u) {
  return __uint_as_float(((unsigned)u) << 16);
}
__device__ __forceinline__ unsigned short f2bf(float f) {
  unsigned u = __float_as_uint(f);
  unsigned r = (u + 0x7FFFu + ((u >> 16) & 1u)) >> 16;  // RNE
  return (unsigned short)r;
}

// ---------------- embed: x[i] = emb[tokens[i]] (fp32 + bf16 mirror) ----------
__global__ __launch_bounds__(256) void k_embed(const int* __restrict__ tokens,
                                               const float* __restrict__ emb,
                                               float* __restrict__ x,
                                               unsigned short* __restrict__ xbf, int n) {
  int i = blockIdx.x * 256 + threadIdx.x;
  if (i < n * HDIM) {
    int node = i >> 6;
    int h = i & 63;
    float v = emb[tokens[node] * HDIM + h];
    x[i] = v;
    xbf[i] = f2bf(v);
  }
}

// ---------------- one-time prep: packed MFMA B-fragments (bf16 hi/lo) --------
__global__ __launch_bounds__(256) void k_prep(const float* __restrict__ W,
                                              const float* __restrict__ w_ih,
                                              const float* __restrict__ w_hh,
                                              unsigned short* __restrict__ wBhi,
                                              unsigned short* __restrict__ wBlo) {
  int o = blockIdx.x * 256 + threadIdx.x;
  if (o >= STEPS * 64 * 512) return;
  int s = o / 32768;
  int r1 = o & 32767;
  int fid = r1 >> 9;
  int le = r1 & 511;
  int lane = le >> 3, j = le & 7;
  int c2 = fid >> 2, t = fid & 3;
  int sec = c2 >> 2, csub = c2 & 3;        // sec: 0=r 1=z 2=gi_n 3=gh_n
  int ch = csub * 16 + (lane & 15);        // channel 0..63
  int k = t * 32 + (lane >> 4) * 8 + j;    // 0..127
  float val = 0.f;
  if (k < 64) {
    if (sec < 3) {
      int jcol = sec * 64 + ch;            // w_ih row
      const float4* a4 = (const float4*)(W + (size_t)s * HDIM * HDIM + (size_t)k * HDIM);
      const float4* b4 = (const float4*)(w_ih + (size_t)jcol * HDIM);
      float acc = 0.f;
#pragma unroll
      for (int q = 0; q < HDIM / 4; ++q) {
        float4 a = a4[q];
        float4 b = b4[q];
        acc = fmaf(a.x, b.x, acc);
        acc = fmaf(a.y, b.y, acc);
        acc = fmaf(a.z, b.z, acc);
        acc = fmaf(a.w, b.w, acc);
      }
      val = acc;
    }
  } else {
    int k2 = k - 64;
    if (sec == 0)      val = w_hh[(size_t)(0 + ch) * HDIM + k2];
    else if (sec == 1) val = w_hh[(size_t)(64 + ch) * HDIM + k2];
    else if (sec == 3) val = w_hh[(size_t)(128 + ch) * HDIM + k2];
  }
  unsigned short hi = f2bf(val);
  unsigned short lo = f2bf(val - bf2f(hi));
  wBhi[o] = hi;
  wBlo[o] = lo;
}

// ---------------- bucketed CSR build (R22 proven: CHUNK=4096) ----------------
__global__ __launch_bounds__(256) void k_bhist(const int* __restrict__ dsts,
                                               int* __restrict__ bcnt,
                                               int ne, int nb, int chunk) {
  __shared__ int h[MAXNB];
  for (int b = threadIdx.x; b < nb; b += 256) h[b] = 0;
  __syncthreads();
  int base = blockIdx.x * chunk;
  int end = base + chunk; if (end > ne) end = ne;
  for (int e = base + threadIdx.x; e < end; e += 256) {
    atomicAdd(&h[dsts[e] >> 6], 1);
  }
  __syncthreads();
  for (int b = threadIdx.x; b < nb; b += 256) {
    int v = h[b];
    if (v > 0) atomicAdd(&bcnt[b], v);
  }
}

__global__ __launch_bounds__(1024) void k_bscan(const int* __restrict__ bcnt,
                                                int* __restrict__ bbase,
                                                int* __restrict__ bcur,
                                                int* __restrict__ rowptr,
                                                int nb, int n, int ne) {
  __shared__ int s[MAXNB];
  const int tid = threadIdx.x;
  int own = (tid < nb) ? bcnt[tid] : 0;
  if (tid < MAXNB) s[tid] = own;
  __syncthreads();
  for (int off = 1; off < MAXNB; off <<= 1) {
    int v = (tid >= off && tid < MAXNB) ? s[tid - off] : 0;
    __syncthreads();
    if (tid < MAXNB) s[tid] += v;
    __syncthreads();
  }
  if (tid < nb) {
    int excl = s[tid] - own;
    bbase[tid] = excl;
    bcur[tid] = excl;
    if (tid == nb - 1) bbase[nb] = excl + own;  // == ne
  }
  if (tid == 0) rowptr[n] = ne;
}

__global__ __launch_bounds__(256) void k_bscatter(const int* __restrict__ srcs,
                                                  const int* __restrict__ dsts,
                                                  int* __restrict__ bcur,
                                                  int* __restrict__ recs,
                                                  int ne, int nb, int chunk) {
  __shared__ int h[MAXNB];
  __shared__ int rsv[MAXNB];
  for (int b = threadIdx.x; b < nb; b += 256) h[b] = 0;
  __syncthreads();
  int base = blockIdx.x * chunk;
  int end = base + chunk; if (end > ne) end = ne;
  for (int e = base + threadIdx.x; e < end; e += 256) {
    atomicAdd(&h[dsts[e] >> 6], 1);
  }
  __syncthreads();
  for (int b = threadIdx.x; b < nb; b += 256) {
    int v = h[b];
    rsv[b] = (v > 0) ? atomicAdd(&bcur[b], v) : 0;
    h[b] = 0;
  }
  __syncthreads();
  for (int e = base + threadIdx.x; e < end; e += 256) {
    int d = dsts[e];
    int b = d >> 6;
    int l = atomicAdd(&h[b], 1);
    recs[rsv[b] + l] = srcs[e] | ((d & 63) << 20);
  }
}

__global__ __launch_bounds__(256) void k_bcsr(const int* __restrict__ bbase,
                                              const int* __restrict__ recs,
                                              int* __restrict__ rowptr,
                                              int* __restrict__ eidx,
                                              int n) {
  __shared__ int cnt[64];
  __shared__ int incl[64];
  const int b = blockIdx.x;
  const int tid = threadIdx.x;
  const int lo = bbase[b], hi = bbase[b + 1];
  if (tid < 64) cnt[tid] = 0;
  __syncthreads();
  for (int e = lo + tid; e < hi; e += 256) {
    atomicAdd(&cnt[(recs[e] >> 20) & 63], 1);
  }
  __syncthreads();
  if (tid < 64) incl[tid] = cnt[tid];
  __syncthreads();
  for (int off = 1; off < 64; off <<= 1) {
    int v = (tid < 64 && tid >= off) ? incl[tid - off] : 0;
    __syncthreads();
    if (tid < 64) incl[tid] += v;
    __syncthreads();
  }
  if (tid < 64) {
    int excl = incl[tid] - cnt[tid];
    int node = b * 64 + tid;
    if (node < n) rowptr[node] = lo + excl;
    cnt[tid] = excl;  // becomes cursor
  }
  __syncthreads();
  for (int e = lo + tid; e < hi; e += 256) {
    int rec = recs[e];
    int dl = (rec >> 20) & 63;
    int pos = atomicAdd(&cnt[dl], 1);
    eidx[lo + pos] = rec & 0xFFFFF;
  }
}

// ---------------- FUSED gather + MFMA GRU ----------------
// R23 structure (bf16 gather mirror + MFMA GRU). R23 counters: FETCH halved
// but dur flat -> gather is REQUEST/LATENCY bound (~2 loads in flight/lane).
// This round: 4-deep per-stream edge unroll (16 edges/iter across 4 streams,
// 4 independent row loads in flight per lane). VGPR was 28 -> registers free.
__global__ __launch_bounds__(512, 2) void k_fgru(const int* __restrict__ rowptr,
                                                 const int* __restrict__ eidx,
                                                 const ushort4* __restrict__ xbf4,
                                                 const float* __restrict__ xin,
                                                 float* __restrict__ xout,
                                                 unsigned short* __restrict__ xbf_out,
                                                 const unsigned short* __restrict__ wBhi_s,
                                                 const unsigned short* __restrict__ wBlo_s,
                                                 const float* __restrict__ b_ih,
                                                 const float* __restrict__ b_hh,
                                                 int n) {
  __shared__ unsigned short Ahi[2][16][136];
  __shared__ unsigned short Alo[2][16][136];

  const int lane = threadIdx.x & 63;
  const int wid = threadIdx.x >> 6;   // 0..7
  const int tile = wid >> 2;          // 0..1
  const int csub = wid & 3;           // 0..3
  const int node_base = blockIdx.x * 32 + tile * 16;

  const int grp = lane >> 4;          // edge stream 0..3
  const int cl = lane & 15;           // 4-channel chunk

#pragma unroll
  for (int q = 0; q < 4; ++q) {
    int i = csub * 4 + q;
    int node = node_base + i;
    float4 acc = make_float4(0.f, 0.f, 0.f, 0.f);
    if (node < n) {
      const int lo = rowptr[node], hi = rowptr[node + 1];
      int e = lo + grp;
      // 4-deep: 4 independent row loads in flight per lane
      for (; e + 12 < hi; e += 16) {
        int s0 = eidx[e];
        int s1 = eidx[e + 4];
        int s2 = eidx[e + 8];
        int s3 = eidx[e + 12];
        ushort4 u0 = xbf4[(size_t)s0 * 16 + cl];
        ushort4 u1 = xbf4[(size_t)s1 * 16 + cl];
        ushort4 u2 = xbf4[(size_t)s2 * 16 + cl];
        ushort4 u3 = xbf4[(size_t)s3 * 16 + cl];
        acc.x += (bf2f(u0.x) + bf2f(u1.x)) + (bf2f(u2.x) + bf2f(u3.x));
        acc.y += (bf2f(u0.y) + bf2f(u1.y)) + (bf2f(u2.y) + bf2f(u3.y));
        acc.z += (bf2f(u0.z) + bf2f(u1.z)) + (bf2f(u2.z) + bf2f(u3.z));
        acc.w += (bf2f(u0.w) + bf2f(u1.w)) + (bf2f(u2.w) + bf2f(u3.w));
      }
      for (; e + 4 < hi; e += 8) {
        int s0 = eidx[e];
        int s1 = eidx[e + 4];
        ushort4 u0 = xbf4[(size_t)s0 * 16 + cl];
        ushort4 u1 = xbf4[(size_t)s1 * 16 + cl];
        acc.x += bf2f(u0.x) + bf2f(u1.x);
        acc.y += bf2f(u0.y) + bf2f(u1.y);
        acc.z += bf2f(u0.z) + bf2f(u1.z);
        acc.w += bf2f(u0.w) + bf2f(u1.w);
      }
      if (e < hi) {
        int s0 = eidx[e];
        ushort4 u0 = xbf4[(size_t)s0 * 16 + cl];
        acc.x += bf2f(u0.x); acc.y += bf2f(u0.y);
        acc.z += bf2f(u0.z); acc.w += bf2f(u0.w);
      }
    }
#pragma unroll
    for (int off = 16; off < 64; off <<= 1) {
      acc.x += __shfl_xor(acc.x, off);
      acc.y += __shfl_xor(acc.y, off);
      acc.z += __shfl_xor(acc.z, off);
      acc.w += __shfl_xor(acc.w, off);
    }
    if (grp == 0) {
      ushort4 hi4, lo4;
      hi4.x = f2bf(acc.x); lo4.x = f2bf(acc.x - bf2f(hi4.x));
      hi4.y = f2bf(acc.y); lo4.y = f2bf(acc.y - bf2f(hi4.y));
      hi4.z = f2bf(acc.z); lo4.z = f2bf(acc.z - bf2f(hi4.z));
      hi4.w = f2bf(acc.w); lo4.w = f2bf(acc.w - bf2f(hi4.w));
      *(ushort4*)&Ahi[tile][i][cl * 4] = hi4;
      *(ushort4*)&Alo[tile][i][cl * 4] = lo4;
    }
    float v = (node < n) ? xin[(size_t)node * HDIM + lane] : 0.f;
    unsigned short hv = f2bf(v);
    Ahi[tile][i][64 + lane] = hv;
    Alo[tile][i][64 + lane] = f2bf(v - bf2f(hv));
  }
  __syncthreads();

  const int row = lane & 15;
  const int kseg = (lane >> 4) * 8;
  s16x8 ah0 = *(const s16x8*)&Ahi[tile][row][0 + kseg];
  s16x8 ah1 = *(const s16x8*)&Ahi[tile][row][32 + kseg];
  s16x8 ah2 = *(const s16x8*)&Ahi[tile][row][64 + kseg];
  s16x8 ah3 = *(const s16x8*)&Ahi[tile][row][96 + kseg];
  s16x8 al0 = *(const s16x8*)&Alo[tile][row][0 + kseg];
  s16x8 al1 = *(const s16x8*)&Alo[tile][row][32 + kseg];
  s16x8 al2 = *(const s16x8*)&Alo[tile][row][64 + kseg];
  s16x8 al3 = *(const s16x8*)&Alo[tile][row][96 + kseg];

  const s16x8* Bh = (const s16x8*)wBhi_s;
  const s16x8* Bl = (const s16x8*)wBlo_s;

  f32x4 accR = {0.f, 0.f, 0.f, 0.f};
  f32x4 accZ = {0.f, 0.f, 0.f, 0.f};
  f32x4 accN = {0.f, 0.f, 0.f, 0.f};
  f32x4 accG = {0.f, 0.f, 0.f, 0.f};

#define MMA3(ACC, AH, AL, FID)                                             \
  {                                                                        \
    s16x8 bh = Bh[(FID) * 64 + lane];                                      \
    s16x8 bl = Bl[(FID) * 64 + lane];                                      \
    ACC = __builtin_amdgcn_mfma_f32_16x16x32_bf16(AH, bh, ACC, 0, 0, 0);   \
    ACC = __builtin_amdgcn_mfma_f32_16x16x32_bf16(AH, bl, ACC, 0, 0, 0);   \
    ACC = __builtin_amdgcn_mfma_f32_16x16x32_bf16(AL, bh, ACC, 0, 0, 0);   \
  }

  {
    const int c2 = 0 + csub;
    MMA3(accR, ah0, al0, c2 * 4 + 0)
    MMA3(accR, ah1, al1, c2 * 4 + 1)
    MMA3(accR, ah2, al2, c2 * 4 + 2)
    MMA3(accR, ah3, al3, c2 * 4 + 3)
  }
  {
    const int c2 = 4 + csub;
    MMA3(accZ, ah0, al0, c2 * 4 + 0)
    MMA3(accZ, ah1, al1, c2 * 4 + 1)
    MMA3(accZ, ah2, al2, c2 * 4 + 2)
    MMA3(accZ, ah3, al3, c2 * 4 + 3)
  }
  {
    const int c2 = 8 + csub;
    MMA3(accN, ah0, al0, c2 * 4 + 0)
    MMA3(accN, ah1, al1, c2 * 4 + 1)
  }
  {
    const int c2 = 12 + csub;
    MMA3(accG, ah2, al2, c2 * 4 + 2)
    MMA3(accG, ah3, al3, c2 * 4 + 3)
  }
#undef MMA3

  const int ch = csub * 16 + (lane & 15);
  const float Br = b_ih[ch] + b_hh[ch];
  const float Bz = b_ih[64 + ch] + b_hh[64 + ch];
  const float Bin = b_ih[128 + ch];
  const float Bhn = b_hh[128 + ch];

#pragma unroll
  for (int reg = 0; reg < 4; ++reg) {
    int i = (lane >> 4) * 4 + reg;
    int node = node_base + i;
    if (node < n) {
      float r = 1.f / (1.f + __expf(-(accR[reg] + Br)));
      float z = 1.f / (1.f + __expf(-(accZ[reg] + Bz)));
      float nn = tanhf((accN[reg] + Bin) + r * (accG[reg] + Bhn));
      float hold = xin[(size_t)node * HDIM + ch];
      float val = (1.f - z) * nn + z * hold;
      xout[(size_t)node * HDIM + ch] = val;
      xbf_out[(size_t)node * HDIM + ch] = f2bf(val);
    }
  }
}

// ---------------- per-graph mean pool of relu(x); batch sorted ----------------
__device__ __forceinline__ int lower_bound_i(const int* __restrict__ a, int n, int v) {
  int lo = 0, hi = n;
  while (lo < hi) {
    int mid = (lo + hi) >> 1;
    if (a[mid] < v) lo = mid + 1; else hi = mid;
  }
  return lo;
}

__global__ __launch_bounds__(256) void k_pool(const float* __restrict__ x,
                                              const int* __restrict__ batch,
                                              float* __restrict__ pooled,
                                              int n) {
  int g = blockIdx.x;
  int lo = lower_bound_i(batch, n, g);
  int hi = lower_bound_i(batch, n, g + 1);
  const int lane = threadIdx.x & 63;
  const int w = threadIdx.x >> 6;  // 0..3
  float acc = 0.f;
  for (int i = lo + w; i < hi; i += 4) {
    acc += fmaxf(x[i * HDIM + lane], 0.f);
  }
  __shared__ float red[4][HDIM];
  red[w][lane] = acc;
  __syncthreads();
  if (w == 0) {
    float s = red[0][lane] + red[1][lane] + red[2][lane] + red[3][lane];
    float cnt = (float)(hi - lo);
    pooled[g * HDIM + lane] = s / fmaxf(cnt, 1.f);
  }
}

// ---------------- head ----------------
__global__ __launch_bounds__(256) void k_head(const float* __restrict__ pooled,
                                              const float* __restrict__ lin1_w,
                                              const float* __restrict__ lin1_b,
                                              const float* __restrict__ lout_w,
                                              const float* __restrict__ lout_b,
                                              float* __restrict__ out, int G) {
  __shared__ float P[128 * HDIM];
  __shared__ float W1T[HDIM * HDIM];
  __shared__ float H1[128 * HDIM];
  for (int t = threadIdx.x; t < G * HDIM; t += 256) P[t] = pooled[t];
  for (int t = threadIdx.x; t < HDIM * HDIM; t += 256) {
    int j = t & 63, k = t >> 6;
    W1T[k * HDIM + j] = lin1_w[j * HDIM + k];
  }
  __syncthreads();
  for (int idx = threadIdx.x; idx < G * HDIM; idx += 256) {
    int g = idx >> 6, j = idx & 63;
    float acc = lin1_b[j];
#pragma unroll
    for (int k = 0; k < HDIM; ++k) acc = fmaf(P[g * HDIM + k], W1T[k * HDIM + j], acc);
    H1[idx] = fmaxf(acc, 0.f);
  }
  __syncthreads();
  for (int idx = threadIdx.x; idx < G * 2; idx += 256) {
    int g = idx >> 1, c = idx & 1;
    float acc = lout_b[c];
#pragma unroll
    for (int j = 0; j < HDIM; ++j) acc = fmaf(H1[g * HDIM + j], lout_w[c * HDIM + j], acc);
    out[idx] = acc;
  }
}

extern "C" void kernel_launch(void* const* d_in, const int* in_sizes, int n_in,
                              void* d_out, int out_size, void* d_ws, size_t ws_size,
                              hipStream_t stream) {
  const int* tokens   = (const int*)d_in[0];
  const int* edge_idx = (const int*)d_in[1];
  const int* batch    = (const int*)d_in[2];
  const float* emb    = (const float*)d_in[3];
  const float* ggnn_w = (const float*)d_in[4];
  const float* w_ih   = (const float*)d_in[5];
  const float* w_hh   = (const float*)d_in[6];
  const float* b_ih   = (const float*)d_in[7];
  const float* b_hh   = (const float*)d_in[8];
  const float* lin1_w = (const float*)d_in[9];
  const float* lin1_b = (const float*)d_in[10];
  const float* lout_w = (const float*)d_in[11];
  const float* lout_b = (const float*)d_in[12];

  const int N = in_sizes[0];
  const int E = in_sizes[1] / 2;
  const int G = out_size / 2;

  const int* srcs = edge_idx;
  const int* dsts = edge_idx + E;

  char* ws = (char*)d_ws;
  size_t off = 0;
  auto take = [&](size_t nbytes) -> char* {
    char* p = ws + off;
    off += (nbytes + 255) & ~(size_t)255;
    return p;
  };
  size_t rowBytes = (size_t)N * HDIM * sizeof(float);
  size_t bfBytes  = (size_t)N * HDIM * sizeof(unsigned short);
  const int NB = (N + 63) / 64;  // <= MAXNB for N <= 65536
  float* xA     = (float*)take(rowBytes);
  float* xB     = (float*)take(rowBytes);
  unsigned short* bfA = (unsigned short*)take(bfBytes);
  unsigned short* bfB = (unsigned short*)take(bfBytes);
  float* pooled = (float*)take((size_t)G * HDIM * sizeof(float));
  unsigned short* wBhi = (unsigned short*)take((size_t)STEPS * 64 * 512 * sizeof(unsigned short));
  unsigned short* wBlo = (unsigned short*)take((size_t)STEPS * 64 * 512 * sizeof(unsigned short));
  int* rowptr   = (int*)take((size_t)(N + 1) * sizeof(int));
  int* bcnt     = (int*)take((size_t)NB * sizeof(int));
  int* bbase    = (int*)take((size_t)(NB + 1) * sizeof(int));
  int* bcur     = (int*)take((size_t)NB * sizeof(int));
  int* recs     = (int*)take((size_t)E * sizeof(int));
  int* eidx     = (int*)take((size_t)E * sizeof(int));

  // --- one-time precompute: packed MFMA weight fragments ---
  {
    const int total = STEPS * 64 * 512;
    k_prep<<<(total + 255) / 256, 256, 0, stream>>>(ggnn_w, w_ih, w_hh, wBhi, wBlo);
  }

  // --- bucketed CSR build (CHUNK=4096, proven R22) ---
  const int CHUNK = 4096;
  const int cblocks = (E + CHUNK - 1) / CHUNK;
  hipMemsetAsync(bcnt, 0, (size_t)NB * sizeof(int), stream);
  k_bhist<<<cblocks, 256, 0, stream>>>(dsts, bcnt, E, NB, CHUNK);
  k_bscan<<<1, 1024, 0, stream>>>(bcnt, bbase, bcur, rowptr, NB, N, E);
  k_bscatter<<<cblocks, 256, 0, stream>>>(srcs, dsts, bcur, recs, E, NB, CHUNK);
  k_bcsr<<<NB, 256, 0, stream>>>(bbase, recs, rowptr, eidx, N);

  // --- embed (fp32 + bf16 mirror) ---
  k_embed<<<(N * HDIM + 255) / 256, 256, 0, stream>>>(tokens, emb, xA, bfA, N);

  // --- GGNN steps: fused gather + MFMA GRU, ping-pong x / xbf ---
  const int fblocks = (N + 31) / 32;
  float* xin = xA;
  float* xout = xB;
  unsigned short* bin = bfA;
  unsigned short* bout = bfB;
  for (int s = 0; s < STEPS; ++s) {
    k_fgru<<<fblocks, 512, 0, stream>>>(rowptr, eidx, (const ushort4*)bin, xin, xout,
                                        bout,
                                        wBhi + (size_t)s * 32768,
                                        wBlo + (size_t)s * 32768,
                                        b_ih, b_hh, N);
    float* t1 = xin; xin = xout; xout = t1;
    unsigned short* t2 = bin; bin = bout; bout = t2;
  }

  k_pool<<<G, 256, 0, stream>>>(xin, batch, pooled, N);
  k_head<<<1, 256, 0, stream>>>(pooled, lin1_w, lin1_b, lout_w, lout_b,
                                (float*)d_out, G);
}

// Round 25
// 233.160 us; speedup vs baseline: 1.9276x; 1.0121x over previous
//
#include <hip/hip_runtime.h>

#define HDIM 64
#define STEPS 3
#define MAXNB 1024  // supports N <= 65536 at 64 nodes/bucket (problem: N=50000)

typedef __attribute__((ext_vector_type(8))) short s16x8;
typedef __attribute__((ext_vector_type(4))) float f32x4;

__device__ __forceinline__ float bf2f(unsigned short u) {
  return __uint_as_float(((unsigned)u) << 16);
}
__device__ __forceinline__ unsigned short f2bf(float f) {
  unsigned u = __float_as_uint(f);
  unsigned r = (u + 0x7FFFu + ((u >> 16) & 1u)) >> 16;  // RNE
  return (unsigned short)r;
}

// ---------------- embed: x[i] = emb[tokens[i]] (fp32 + bf16 mirror) ----------
__global__ __launch_bounds__(256) void k_embed(const int* __restrict__ tokens,
                                               const float* __restrict__ emb,
                                               float* __restrict__ x,
                                               unsigned short* __restrict__ xbf, int n) {
  int i = blockIdx.x * 256 + threadIdx.x;
  if (i < n * HDIM) {
    int node = i >> 6;
    int h = i & 63;
    float v = emb[tokens[node] * HDIM + h];
    x[i] = v;
    xbf[i] = f2bf(v);
  }
}

// ---------------- one-time prep: packed MFMA B-fragments (bf16 hi/lo) --------
// ALSO zeroes bcnt (replaces hipMemsetAsync whose fillBufferAligned kernel
// measured 45us for 3KB in the captured graph - R24 profile).
__global__ __launch_bounds__(256) void k_prep(const float* __restrict__ W,
                                              const float* __restrict__ w_ih,
                                              const float* __restrict__ w_hh,
                                              unsigned short* __restrict__ wBhi,
                                              unsigned short* __restrict__ wBlo,
                                              int* __restrict__ bcnt, int nb) {
  int o = blockIdx.x * 256 + threadIdx.x;
  if (o < nb) bcnt[o] = 0;
  if (o >= STEPS * 64 * 512) return;
  int s = o / 32768;
  int r1 = o & 32767;
  int fid = r1 >> 9;
  int le = r1 & 511;
  int lane = le >> 3, j = le & 7;
  int c2 = fid >> 2, t = fid & 3;
  int sec = c2 >> 2, csub = c2 & 3;        // sec: 0=r 1=z 2=gi_n 3=gh_n
  int ch = csub * 16 + (lane & 15);        // channel 0..63
  int k = t * 32 + (lane >> 4) * 8 + j;    // 0..127
  float val = 0.f;
  if (k < 64) {
    if (sec < 3) {
      int jcol = sec * 64 + ch;            // w_ih row
      const float4* a4 = (const float4*)(W + (size_t)s * HDIM * HDIM + (size_t)k * HDIM);
      const float4* b4 = (const float4*)(w_ih + (size_t)jcol * HDIM);
      float acc = 0.f;
#pragma unroll
      for (int q = 0; q < HDIM / 4; ++q) {
        float4 a = a4[q];
        float4 b = b4[q];
        acc = fmaf(a.x, b.x, acc);
        acc = fmaf(a.y, b.y, acc);
        acc = fmaf(a.z, b.z, acc);
        acc = fmaf(a.w, b.w, acc);
      }
      val = acc;
    }
  } else {
    int k2 = k - 64;
    if (sec == 0)      val = w_hh[(size_t)(0 + ch) * HDIM + k2];
    else if (sec == 1) val = w_hh[(size_t)(64 + ch) * HDIM + k2];
    else if (sec == 3) val = w_hh[(size_t)(128 + ch) * HDIM + k2];
  }
  unsigned short hi = f2bf(val);
  unsigned short lo = f2bf(val - bf2f(hi));
  wBhi[o] = hi;
  wBlo[o] = lo;
}

// ---------------- bucketed CSR build (R22 proven: CHUNK=4096) ----------------
__global__ __launch_bounds__(256) void k_bhist(const int* __restrict__ dsts,
                                               int* __restrict__ bcnt,
                                               int ne, int nb, int chunk) {
  __shared__ int h[MAXNB];
  for (int b = threadIdx.x; b < nb; b += 256) h[b] = 0;
  __syncthreads();
  int base = blockIdx.x * chunk;
  int end = base + chunk; if (end > ne) end = ne;
  for (int e = base + threadIdx.x; e < end; e += 256) {
    atomicAdd(&h[dsts[e] >> 6], 1);
  }
  __syncthreads();
  for (int b = threadIdx.x; b < nb; b += 256) {
    int v = h[b];
    if (v > 0) atomicAdd(&bcnt[b], v);
  }
}

__global__ __launch_bounds__(1024) void k_bscan(const int* __restrict__ bcnt,
                                                int* __restrict__ bbase,
                                                int* __restrict__ bcur,
                                                int* __restrict__ rowptr,
                                                int nb, int n, int ne) {
  __shared__ int s[MAXNB];
  const int tid = threadIdx.x;
  int own = (tid < nb) ? bcnt[tid] : 0;
  if (tid < MAXNB) s[tid] = own;
  __syncthreads();
  for (int off = 1; off < MAXNB; off <<= 1) {
    int v = (tid >= off && tid < MAXNB) ? s[tid - off] : 0;
    __syncthreads();
    if (tid < MAXNB) s[tid] += v;
    __syncthreads();
  }
  if (tid < nb) {
    int excl = s[tid] - own;
    bbase[tid] = excl;
    bcur[tid] = excl;
    if (tid == nb - 1) bbase[nb] = excl + own;  // == ne
  }
  if (tid == 0) rowptr[n] = ne;
}

__global__ __launch_bounds__(256) void k_bscatter(const int* __restrict__ srcs,
                                                  const int* __restrict__ dsts,
                                                  int* __restrict__ bcur,
                                                  int* __restrict__ recs,
                                                  int ne, int nb, int chunk) {
  __shared__ int h[MAXNB];
  __shared__ int rsv[MAXNB];
  for (int b = threadIdx.x; b < nb; b += 256) h[b] = 0;
  __syncthreads();
  int base = blockIdx.x * chunk;
  int end = base + chunk; if (end > ne) end = ne;
  for (int e = base + threadIdx.x; e < end; e += 256) {
    atomicAdd(&h[dsts[e] >> 6], 1);
  }
  __syncthreads();
  for (int b = threadIdx.x; b < nb; b += 256) {
    int v = h[b];
    rsv[b] = (v > 0) ? atomicAdd(&bcur[b], v) : 0;
    h[b] = 0;
  }
  __syncthreads();
  for (int e = base + threadIdx.x; e < end; e += 256) {
    int d = dsts[e];
    int b = d >> 6;
    int l = atomicAdd(&h[b], 1);
    recs[rsv[b] + l] = srcs[e] | ((d & 63) << 20);
  }
}

__global__ __launch_bounds__(256) void k_bcsr(const int* __restrict__ bbase,
                                              const int* __restrict__ recs,
                                              int* __restrict__ rowptr,
                                              int* __restrict__ eidx,
                                              int n) {
  __shared__ int cnt[64];
  __shared__ int incl[64];
  const int b = blockIdx.x;
  const int tid = threadIdx.x;
  const int lo = bbase[b], hi = bbase[b + 1];
  if (tid < 64) cnt[tid] = 0;
  __syncthreads();
  for (int e = lo + tid; e < hi; e += 256) {
    atomicAdd(&cnt[(recs[e] >> 20) & 63], 1);
  }
  __syncthreads();
  if (tid < 64) incl[tid] = cnt[tid];
  __syncthreads();
  for (int off = 1; off < 64; off <<= 1) {
    int v = (tid < 64 && tid >= off) ? incl[tid - off] : 0;
    __syncthreads();
    if (tid < 64) incl[tid] += v;
    __syncthreads();
  }
  if (tid < 64) {
    int excl = incl[tid] - cnt[tid];
    int node = b * 64 + tid;
    if (node < n) rowptr[node] = lo + excl;
    cnt[tid] = excl;  // becomes cursor
  }
  __syncthreads();
  for (int e = lo + tid; e < hi; e += 256) {
    int rec = recs[e];
    int dl = (rec >> 20) & 63;
    int pos = atomicAdd(&cnt[dl], 1);
    eidx[lo + pos] = rec & 0xFFFFF;
  }
}

// ---------------- FUSED gather + MFMA GRU (R24, passed, at latency floor) ----
__global__ __launch_bounds__(512, 2) void k_fgru(const int* __restrict__ rowptr,
                                                 const int* __restrict__ eidx,
                                                 const ushort4* __restrict__ xbf4,
                                                 const float* __restrict__ xin,
                                                 float* __restrict__ xout,
                                                 unsigned short* __restrict__ xbf_out,
                                                 const unsigned short* __restrict__ wBhi_s,
                                                 const unsigned short* __restrict__ wBlo_s,
                                                 const float* __restrict__ b_ih,
                                                 const float* __restrict__ b_hh,
                                                 int n) {
  __shared__ unsigned short Ahi[2][16][136];
  __shared__ unsigned short Alo[2][16][136];

  const int lane = threadIdx.x & 63;
  const int wid = threadIdx.x >> 6;   // 0..7
  const int tile = wid >> 2;          // 0..1
  const int csub = wid & 3;           // 0..3
  const int node_base = blockIdx.x * 32 + tile * 16;

  const int grp = lane >> 4;          // edge stream 0..3
  const int cl = lane & 15;           // 4-channel chunk

#pragma unroll
  for (int q = 0; q < 4; ++q) {
    int i = csub * 4 + q;
    int node = node_base + i;
    float4 acc = make_float4(0.f, 0.f, 0.f, 0.f);
    if (node < n) {
      const int lo = rowptr[node], hi = rowptr[node + 1];
      int e = lo + grp;
      for (; e + 12 < hi; e += 16) {
        int s0 = eidx[e];
        int s1 = eidx[e + 4];
        int s2 = eidx[e + 8];
        int s3 = eidx[e + 12];
        ushort4 u0 = xbf4[(size_t)s0 * 16 + cl];
        ushort4 u1 = xbf4[(size_t)s1 * 16 + cl];
        ushort4 u2 = xbf4[(size_t)s2 * 16 + cl];
        ushort4 u3 = xbf4[(size_t)s3 * 16 + cl];
        acc.x += (bf2f(u0.x) + bf2f(u1.x)) + (bf2f(u2.x) + bf2f(u3.x));
        acc.y += (bf2f(u0.y) + bf2f(u1.y)) + (bf2f(u2.y) + bf2f(u3.y));
        acc.z += (bf2f(u0.z) + bf2f(u1.z)) + (bf2f(u2.z) + bf2f(u3.z));
        acc.w += (bf2f(u0.w) + bf2f(u1.w)) + (bf2f(u2.w) + bf2f(u3.w));
      }
      for (; e + 4 < hi; e += 8) {
        int s0 = eidx[e];
        int s1 = eidx[e + 4];
        ushort4 u0 = xbf4[(size_t)s0 * 16 + cl];
        ushort4 u1 = xbf4[(size_t)s1 * 16 + cl];
        acc.x += bf2f(u0.x) + bf2f(u1.x);
        acc.y += bf2f(u0.y) + bf2f(u1.y);
        acc.z += bf2f(u0.z) + bf2f(u1.z);
        acc.w += bf2f(u0.w) + bf2f(u1.w);
      }
      if (e < hi) {
        int s0 = eidx[e];
        ushort4 u0 = xbf4[(size_t)s0 * 16 + cl];
        acc.x += bf2f(u0.x); acc.y += bf2f(u0.y);
        acc.z += bf2f(u0.z); acc.w += bf2f(u0.w);
      }
    }
#pragma unroll
    for (int off = 16; off < 64; off <<= 1) {
      acc.x += __shfl_xor(acc.x, off);
      acc.y += __shfl_xor(acc.y, off);
      acc.z += __shfl_xor(acc.z, off);
      acc.w += __shfl_xor(acc.w, off);
    }
    if (grp == 0) {
      ushort4 hi4, lo4;
      hi4.x = f2bf(acc.x); lo4.x = f2bf(acc.x - bf2f(hi4.x));
      hi4.y = f2bf(acc.y); lo4.y = f2bf(acc.y - bf2f(hi4.y));
      hi4.z = f2bf(acc.z); lo4.z = f2bf(acc.z - bf2f(hi4.z));
      hi4.w = f2bf(acc.w); lo4.w = f2bf(acc.w - bf2f(hi4.w));
      *(ushort4*)&Ahi[tile][i][cl * 4] = hi4;
      *(ushort4*)&Alo[tile][i][cl * 4] = lo4;
    }
    float v = (node < n) ? xin[(size_t)node * HDIM + lane] : 0.f;
    unsigned short hv = f2bf(v);
    Ahi[tile][i][64 + lane] = hv;
    Alo[tile][i][64 + lane] = f2bf(v - bf2f(hv));
  }
  __syncthreads();

  const int row = lane & 15;
  const int kseg = (lane >> 4) * 8;
  s16x8 ah0 = *(const s16x8*)&Ahi[tile][row][0 + kseg];
  s16x8 ah1 = *(const s16x8*)&Ahi[tile][row][32 + kseg];
  s16x8 ah2 = *(const s16x8*)&Ahi[tile][row][64 + kseg];
  s16x8 ah3 = *(const s16x8*)&Ahi[tile][row][96 + kseg];
  s16x8 al0 = *(const s16x8*)&Alo[tile][row][0 + kseg];
  s16x8 al1 = *(const s16x8*)&Alo[tile][row][32 + kseg];
  s16x8 al2 = *(const s16x8*)&Alo[tile][row][64 + kseg];
  s16x8 al3 = *(const s16x8*)&Alo[tile][row][96 + kseg];

  const s16x8* Bh = (const s16x8*)wBhi_s;
  const s16x8* Bl = (const s16x8*)wBlo_s;

  f32x4 accR = {0.f, 0.f, 0.f, 0.f};
  f32x4 accZ = {0.f, 0.f, 0.f, 0.f};
  f32x4 accN = {0.f, 0.f, 0.f, 0.f};
  f32x4 accG = {0.f, 0.f, 0.f, 0.f};

#define MMA3(ACC, AH, AL, FID)                                             \
  {                                                                        \
    s16x8 bh = Bh[(FID) * 64 + lane];                                      \
    s16x8 bl = Bl[(FID) * 64 + lane];                                      \
    ACC = __builtin_amdgcn_mfma_f32_16x16x32_bf16(AH, bh, ACC, 0, 0, 0);   \
    ACC = __builtin_amdgcn_mfma_f32_16x16x32_bf16(AH, bl, ACC, 0, 0, 0);   \
    ACC = __builtin_amdgcn_mfma_f32_16x16x32_bf16(AL, bh, ACC, 0, 0, 0);   \
  }

  {
    const int c2 = 0 + csub;
    MMA3(accR, ah0, al0, c2 * 4 + 0)
    MMA3(accR, ah1, al1, c2 * 4 + 1)
    MMA3(accR, ah2, al2, c2 * 4 + 2)
    MMA3(accR, ah3, al3, c2 * 4 + 3)
  }
  {
    const int c2 = 4 + csub;
    MMA3(accZ, ah0, al0, c2 * 4 + 0)
    MMA3(accZ, ah1, al1, c2 * 4 + 1)
    MMA3(accZ, ah2, al2, c2 * 4 + 2)
    MMA3(accZ, ah3, al3, c2 * 4 + 3)
  }
  {
    const int c2 = 8 + csub;
    MMA3(accN, ah0, al0, c2 * 4 + 0)
    MMA3(accN, ah1, al1, c2 * 4 + 1)
  }
  {
    const int c2 = 12 + csub;
    MMA3(accG, ah2, al2, c2 * 4 + 2)
    MMA3(accG, ah3, al3, c2 * 4 + 3)
  }
#undef MMA3

  const int ch = csub * 16 + (lane & 15);
  const float Br = b_ih[ch] + b_hh[ch];
  const float Bz = b_ih[64 + ch] + b_hh[64 + ch];
  const float Bin = b_ih[128 + ch];
  const float Bhn = b_hh[128 + ch];

#pragma unroll
  for (int reg = 0; reg < 4; ++reg) {
    int i = (lane >> 4) * 4 + reg;
    int node = node_base + i;
    if (node < n) {
      float r = 1.f / (1.f + __expf(-(accR[reg] + Br)));
      float z = 1.f / (1.f + __expf(-(accZ[reg] + Bz)));
      float nn = tanhf((accN[reg] + Bin) + r * (accG[reg] + Bhn));
      float hold = xin[(size_t)node * HDIM + ch];
      float val = (1.f - z) * nn + z * hold;
      xout[(size_t)node * HDIM + ch] = val;
      xbf_out[(size_t)node * HDIM + ch] = f2bf(val);
    }
  }
}

// ---------------- per-graph mean pool of relu(x); batch sorted ----------------
__device__ __forceinline__ int lower_bound_i(const int* __restrict__ a, int n, int v) {
  int lo = 0, hi = n;
  while (lo < hi) {
    int mid = (lo + hi) >> 1;
    if (a[mid] < v) lo = mid + 1; else hi = mid;
  }
  return lo;
}

__global__ __launch_bounds__(256) void k_pool(const float* __restrict__ x,
                                              const int* __restrict__ batch,
                                              float* __restrict__ pooled,
                                              int n) {
  int g = blockIdx.x;
  int lo = lower_bound_i(batch, n, g);
  int hi = lower_bound_i(batch, n, g + 1);
  const int lane = threadIdx.x & 63;
  const int w = threadIdx.x >> 6;  // 0..3
  float acc = 0.f;
  for (int i = lo + w; i < hi; i += 4) {
    acc += fmaxf(x[i * HDIM + lane], 0.f);
  }
  __shared__ float red[4][HDIM];
  red[w][lane] = acc;
  __syncthreads();
  if (w == 0) {
    float s = red[0][lane] + red[1][lane] + red[2][lane] + red[3][lane];
    float cnt = (float)(hi - lo);
    pooled[g * HDIM + lane] = s / fmaxf(cnt, 1.f);
  }
}

// ---------------- head ----------------
__global__ __launch_bounds__(256) void k_head(const float* __restrict__ pooled,
                                              const float* __restrict__ lin1_w,
                                              const float* __restrict__ lin1_b,
                                              const float* __restrict__ lout_w,
                                              const float* __restrict__ lout_b,
                                              float* __restrict__ out, int G) {
  __shared__ float P[128 * HDIM];
  __shared__ float W1T[HDIM * HDIM];
  __shared__ float H1[128 * HDIM];
  for (int t = threadIdx.x; t < G * HDIM; t += 256) P[t] = pooled[t];
  for (int t = threadIdx.x; t < HDIM * HDIM; t += 256) {
    int j = t & 63, k = t >> 6;
    W1T[k * HDIM + j] = lin1_w[j * HDIM + k];
  }
  __syncthreads();
  for (int idx = threadIdx.x; idx < G * HDIM; idx += 256) {
    int g = idx >> 6, j = idx & 63;
    float acc = lin1_b[j];
#pragma unroll
    for (int k = 0; k < HDIM; ++k) acc = fmaf(P[g * HDIM + k], W1T[k * HDIM + j], acc);
    H1[idx] = fmaxf(acc, 0.f);
  }
  __syncthreads();
  for (int idx = threadIdx.x; idx < G * 2; idx += 256) {
    int g = idx >> 1, c = idx & 1;
    float acc = lout_b[c];
#pragma unroll
    for (int j = 0; j < HDIM; ++j) acc = fmaf(H1[g * HDIM + j], lout_w[c * HDIM + j], acc);
    out[idx] = acc;
  }
}

extern "C" void kernel_launch(void* const* d_in, const int* in_sizes, int n_in,
                              void* d_out, int out_size, void* d_ws, size_t ws_size,
                              hipStream_t stream) {
  const int* tokens   = (const int*)d_in[0];
  const int* edge_idx = (const int*)d_in[1];
  const int* batch    = (const int*)d_in[2];
  const float* emb    = (const float*)d_in[3];
  const float* ggnn_w = (const float*)d_in[4];
  const float* w_ih   = (const float*)d_in[5];
  const float* w_hh   = (const float*)d_in[6];
  const float* b_ih   = (const float*)d_in[7];
  const float* b_hh   = (const float*)d_in[8];
  const float* lin1_w = (const float*)d_in[9];
  const float* lin1_b = (const float*)d_in[10];
  const float* lout_w = (const float*)d_in[11];
  const float* lout_b = (const float*)d_in[12];

  const int N = in_sizes[0];
  const int E = in_sizes[1] / 2;
  const int G = out_size / 2;

  const int* srcs = edge_idx;
  const int* dsts = edge_idx + E;

  char* ws = (char*)d_ws;
  size_t off = 0;
  auto take = [&](size_t nbytes) -> char* {
    char* p = ws + off;
    off += (nbytes + 255) & ~(size_t)255;
    return p;
  };
  size_t rowBytes = (size_t)N * HDIM * sizeof(float);
  size_t bfBytes  = (size_t)N * HDIM * sizeof(unsigned short);
  const int NB = (N + 63) / 64;  // <= MAXNB for N <= 65536
  float* xA     = (float*)take(rowBytes);
  float* xB     = (float*)take(rowBytes);
  unsigned short* bfA = (unsigned short*)take(bfBytes);
  unsigned short* bfB = (unsigned short*)take(bfBytes);
  float* pooled = (float*)take((size_t)G * HDIM * sizeof(float));
  unsigned short* wBhi = (unsigned short*)take((size_t)STEPS * 64 * 512 * sizeof(unsigned short));
  unsigned short* wBlo = (unsigned short*)take((size_t)STEPS * 64 * 512 * sizeof(unsigned short));
  int* rowptr   = (int*)take((size_t)(N + 1) * sizeof(int));
  int* bcnt     = (int*)take((size_t)NB * sizeof(int));
  int* bbase    = (int*)take((size_t)(NB + 1) * sizeof(int));
  int* bcur     = (int*)take((size_t)NB * sizeof(int));
  int* recs     = (int*)take((size_t)E * sizeof(int));
  int* eidx     = (int*)take((size_t)E * sizeof(int));

  // --- one-time precompute: packed MFMA weight fragments + bcnt zeroing ---
  {
    const int total = STEPS * 64 * 512;
    k_prep<<<(total + 255) / 256, 256, 0, stream>>>(ggnn_w, w_ih, w_hh, wBhi, wBlo,
                                                    bcnt, NB);
  }

  // --- bucketed CSR build (CHUNK=4096, proven R22) ---
  const int CHUNK = 4096;
  const int cblocks = (E + CHUNK - 1) / CHUNK;
  k_bhist<<<cblocks, 256, 0, stream>>>(dsts, bcnt, E, NB, CHUNK);
  k_bscan<<<1, 1024, 0, stream>>>(bcnt, bbase, bcur, rowptr, NB, N, E);
  k_bscatter<<<cblocks, 256, 0, stream>>>(srcs, dsts, bcur, recs, E, NB, CHUNK);
  k_bcsr<<<NB, 256, 0, stream>>>(bbase, recs, rowptr, eidx, N);

  // --- embed (fp32 + bf16 mirror) ---
  k_embed<<<(N * HDIM + 255) / 256, 256, 0, stream>>>(tokens, emb, xA, bfA, N);

  // --- GGNN steps: fused gather + MFMA GRU, ping-pong x / xbf ---
  const int fblocks = (N + 31) / 32;
  float* xin = xA;
  float* xout = xB;
  unsigned short* bin = bfA;
  unsigned short* bout = bfB;
  for (int s = 0; s < STEPS; ++s) {
    k_fgru<<<fblocks, 512, 0, stream>>>(rowptr, eidx, (const ushort4*)bin, xin, xout,
                                        bout,
                                        wBhi + (size_t)s * 32768,
                                        wBlo + (size_t)s * 32768,
                                        b_ih, b_hh, N);
    float* t1 = xin; xin = xout; xout = t1;
    unsigned short* t2 = bin; bin = bout; bout = t2;
  }

  k_pool<<<G, 256, 0, stream>>>(xin, batch, pooled, N);
  k_head<<<1, 256, 0, stream>>>(pooled, lin1_w, lin1_b, lout_w, lout_b,
                                (float*)d_out, G);
}